// Round 5
// baseline (366.221 us; speedup 1.0000x reference)
//
#include <hip/hip_runtime.h>
#include <math.h>

// Problem: B=8, V=8, N=1000, D=256, H=8, KS=32
// Single-launch fused decoder: 512 blocks x 256 threads.
// block: b = blk&7, c = (blk>>3)&7 (node slice of 125), h = blk>>6 (head)
//
// ws float offsets (all partial slots; NO zero-init required anywhere)
#define OFF_MWV    0                        // Mw rows 0..255   [256*8]
#define OFF_MWL    2048                     // Mw rows 512..767 [256*8]
#define OFF_CSUMP  4096                     // [512]
#define OFF_HSTATP 4608                     // [512*256]
#define OFF_S8P    135680                   // [512*64]
#define OFF_FLAG1  168448                   // [512]
#define OFF_FQ     168960                   // [64*256]
#define OFF_LQM    185344                   // [64*8]
#define OFF_FLAG2  185856                   // [64]
#define OFF_EXPSP  185920                   // [512]
#define OFF_PACKP  186432                   // [512 u64] = 1024 floats
#define OFF_FLAG3  187456                   // [512]  -> total ~188k floats (752 KB)

__device__ inline float waveSum(float v){
  #pragma unroll
  for (int o = 32; o > 0; o >>= 1) v += __shfl_down(v, o, 64);
  return v;
}
__device__ inline unsigned long long waveMaxU(unsigned long long v){
  #pragma unroll
  for (int o = 32; o > 0; o >>= 1) {
    unsigned long long w = __shfl_down(v, o, 64);
    v = (w > v) ? w : v;
  }
  return v;
}
__device__ inline unsigned encF(float f){
  unsigned u = __float_as_uint(f);
  return (u & 0x80000000u) ? ~u : (u | 0x80000000u);
}
__device__ inline float decF(unsigned u){
  return (u & 0x80000000u) ? __uint_as_float(u & 0x7fffffffu)
                           : __uint_as_float(~u);
}
__device__ inline void spinFlag(float* f){
  while (atomicAdd(f, 0.0f) != 1.0f) __builtin_amdgcn_s_sleep(2);
}

// launch_bounds (256,2): >=2 waves/EU => >=2 blocks/CU => all 512 blocks
// co-resident (LDS ~24KB => 6/CU anyway). Spin-waits are deadlock-free.
__global__ __launch_bounds__(256, 2) void fused_all(
    const float* __restrict__ node_dyn, const float* __restrict__ gVs,
    const float* __restrict__ gKs, const float* __restrict__ lKs,
    const void* __restrict__ maskp, const float* __restrict__ fixedc,
    const float* __restrict__ prev, const float* __restrict__ veh,
    const float* __restrict__ pcs, const float* __restrict__ pns1,
    const float* __restrict__ pns2, const float* __restrict__ po,
    float* __restrict__ W, float* __restrict__ out)
{
  const int blk = blockIdx.x, tid = threadIdx.x;
  const int b = blk & 7, c = (blk >> 3) & 7, h = blk >> 6;
  const int n0 = c * 125;

  float* mwgV    = W + OFF_MWV;
  float* mwgL    = W + OFF_MWL;
  float* csum_p  = W + OFF_CSUMP;
  float* hstat_p = W + OFF_HSTATP;
  float* s8_p    = W + OFF_S8P;
  float* flag1   = W + OFF_FLAG1;
  float* fqg     = W + OFF_FQ;
  float* lqmg    = W + OFF_LQM;
  float* flag2   = W + OFF_FLAG2;
  float* expsum_p= W + OFF_EXPSP;
  unsigned long long* packed_p = (unsigned long long*)(W + OFF_PACKP);
  float* flag3   = W + OFF_FLAG3;

  // LDS: two aliased regions + small persistent arrays (~24 KB total)
  __shared__ __align__(16) float smemA[2112];   // cvs -> p
  __shared__ __align__(16) float U2[2048];      // redA -> hstatF -> fqL
  __shared__ __align__(16) float mwk[256];      // K-part Mw rows [32][8]
  __shared__ __align__(16) float gq[256];       // [v][k]
  __shared__ float qmk[64];                     // [v][f]
  __shared__ float csumF[8];
  __shared__ float s8F[512];
  __shared__ __align__(16) float cl[256];
  __shared__ float fql[256];
  __shared__ float part[256];
  __shared__ float lqmL[64];
  __shared__ float red4[4];
  __shared__ unsigned long long rP[4];
  __shared__ int bytemode;

  // ---- mask dtype auto-detect (bool-u8 vs int32) ----
  if (tid == 0) {
    int bm = 0;
    const unsigned char* mb = (const unsigned char*)maskp;
    for (int idx = 1; idx < 256; idx++)
      if ((idx & 3) != 0 && mb[idx] != 0) { bm = 1; break; }
    bytemode = bm;
  }

  // ---- stage A0: load cvs [8][264] into smemA ----
  for (int idx = tid; idx < 2048; idx += 256) {
    int v = idx >> 8, j = idx & 255;
    smemA[v * 264 + j] = prev[(size_t)(b * 8 + v) * 256 + j];
  }
  if (tid < 64) {
    int v = tid >> 3, j = tid & 7;
    smemA[v * 264 + 256 + j] = veh[(b * 8 + v) * 8 + j];
  }

  // ---- stage A1: Mw row sets. set0 = K rows (256+h*32..) -> LDS mwk.
  //      blocks (b==0,c==0): also V rows (h*32..) -> global
  //      blocks (b==0,c==1): also L rows (512+h*32..) -> global
  {
    int nsets = (b == 0 && c < 2) ? 2 : 1;
    int k = tid >> 3, prt = tid & 7;            // 32 rows x 8 partials
    for (int set = 0; set < nsets; set++) {
      int i0 = (set == 0) ? (256 + h * 32) : ((c == 0) ? h * 32 : 512 + h * 32);
      int i = i0 + k;
      const float* row = pns2 + (size_t)i * 769;
      float acc[7] = {0.f,0.f,0.f,0.f,0.f,0.f,0.f};
      for (int t = 0; t < 96; t++) {
        int j = prt + 8 * t;
        float r = row[j];
        const float* w = pns1 + j * 7;
        #pragma unroll
        for (int f = 0; f < 7; f++) acc[f] += r * w[f];
      }
      __syncthreads();   // U2 free (prev iteration consumed)
      #pragma unroll
      for (int f = 0; f < 7; f++) U2[k * 64 + prt * 8 + f] = acc[f];
      __syncthreads();
      int k2 = tid >> 3, f2 = tid & 7;
      int i2 = i0 + k2;
      float val;
      if (f2 < 7) {
        float s = 0.f;
        #pragma unroll
        for (int p2 = 0; p2 < 8; p2++) s += U2[k2 * 64 + p2 * 8 + f2];
        val = pns1[i2 * 7 + f2] + s;
      } else {
        val = pns2[(size_t)i2 * 769 + 768];
      }
      if (set == 0) mwk[k2 * 8 + f2] = val;
      else {
        float* dst = (c == 0) ? (mwgV + (h * 32) * 8) : (mwgL + (h * 32) * 8);
        dst[k2 * 8 + f2] = val;
      }
    }
  }
  __syncthreads();   // cvs + mwk ready, bytemode ready

  // ---- stage A2: gq[v][k] and qmk[v][f] ----
  {
    int v = tid >> 5, k = tid & 31, d = h * 32 + k;
    float a = fixedc[b * 256 + d];
    const float4* c4 = (const float4*)(smemA + v * 264);
    const float4* w4 = (const float4*)(pcs + (size_t)d * 264);
    #pragma unroll 4
    for (int e = 0; e < 66; e++) {
      float4 cv = c4[e], wv = w4[e];
      a += cv.x*wv.x + cv.y*wv.y + cv.z*wv.z + cv.w*wv.w;
    }
    gq[tid] = a;
  }
  __syncthreads();
  if (tid < 64) {
    int v = tid >> 3, f = tid & 7;
    float a = 0.f;
    for (int k = 0; k < 32; k++) a += gq[v * 32 + k] * mwk[k * 8 + f];
    qmk[tid] = a;
  }
  __syncthreads();   // also: cvs dead -> smemA reusable as p[1000]

  // ---- stage B: compat -> exp -> partial slots (plain stores) ----
  float* p = smemA;
  {
    float tsum = 0.f;
    for (int e = tid; e < 1000; e += 256) {
      int v = e / 125;
      int n = n0 + (e - v * 125);
      int bvn = (b * 8 + v) * 1000 + n;
      const float4* nd4 = (const float4*)(node_dyn + (size_t)bvn * 8);
      float4 ndA = nd4[0], ndB = nd4[1];
      const float4* gk4 = (const float4*)(gKs + ((size_t)(h * 8 + b) * 1000 + n) * 32);
      const float4* gq4 = (const float4*)(gq + v * 32);
      float s = 0.f;
      #pragma unroll
      for (int k4 = 0; k4 < 8; k4++) {
        float4 g = gk4[k4], q = gq4[k4];
        s += g.x*q.x + g.y*q.y + g.z*q.z + g.w*q.w;
      }
      const float* qm = qmk + v * 8;
      float dyn = ndA.x*qm[0] + ndA.y*qm[1] + ndA.z*qm[2] + ndA.w*qm[3]
                + ndB.x*qm[4] + ndB.y*qm[5] + ndB.z*qm[6] + ndB.w*qm[7];
      bool on = bytemode ? (((const unsigned char*)maskp)[bvn] != 0)
                         : (((const int*)maskp)[bvn] != 0);
      float cc = (s + dyn) * 0.17677669529663687f + (on ? 0.f : -INFINITY);
      float pv = __expf(cc);          // no max-sub: |cc| small, shift-invariant
      p[e] = pv;
      tsum += pv;
    }
    tsum = waveSum(tsum);
    if ((tid & 63) == 0) red4[tid >> 6] = tsum;
    __syncthreads();
    if (tid == 0) csum_p[blk] = red4[0] + red4[1] + red4[2] + red4[3];
    // hstat partial [v][k]
    {
      int v = tid >> 5, k = tid & 31;
      const float* gv = gVs + ((size_t)(h * 8 + b) * 1000 + n0) * 32 + k;
      const float* pr = p + v * 125;
      float a = 0.f;
      #pragma unroll 5
      for (int i = 0; i < 125; i++) a += pr[i] * gv[(size_t)i * 32];
      hstat_p[(size_t)blk * 256 + tid] = a;
    }
    // s8 partial [v][f]
    if (tid < 64) {
      int v = tid >> 3, f = tid & 7;
      const float* nd = node_dyn + ((size_t)(b * 8 + v) * 1000 + n0) * 8 + f;
      const float* pr = p + v * 125;
      float a = 0.f;
      #pragma unroll 5
      for (int i = 0; i < 125; i++) a += pr[i] * nd[i * 8];
      s8_p[(size_t)blk * 64 + tid] = a;
    }
    __threadfence();          // release partials (incl. Mw writers' rows)
    __syncthreads();
    if (tid == 0) atomicExch(&flag1[blk], 1.0f);
  }

  // ---- stage E (h==0 blocks only; 64 blocks, one bv = b*8+c each):
  //      reduce partials for b -> conc -> fq -> lqm ----
  if (h == 0) {
    spinFlag(&flag1[tid]);
    spinFlag(&flag1[tid + 256]);
    __threadfence();          // acquire
    __syncthreads();
    float* hstatF = U2;
    for (int h2 = 0; h2 < 8; h2++) {
      float s = 0.f;
      #pragma unroll
      for (int cc = 0; cc < 8; cc++)
        s += hstat_p[(size_t)((h2 << 6) | (cc << 3) | b) * 256 + tid];
      hstatF[h2 * 256 + tid] = s;
    }
    if (tid < 8) {
      float s = 0.f;
      #pragma unroll
      for (int cc = 0; cc < 8; cc++) s += csum_p[(tid << 6) | (cc << 3) | b];
      csumF[tid] = s;
    }
    for (int idx = tid; idx < 512; idx += 256) {
      int h2 = idx >> 6, vf = idx & 63;
      float s = 0.f;
      #pragma unroll
      for (int cc = 0; cc < 8; cc++)
        s += s8_p[(size_t)((h2 << 6) | (cc << 3) | b) * 64 + vf];
      s8F[idx] = s;
    }
    __syncthreads();
    // conc (cl) for v = c
    {
      int h2 = tid >> 5, k2 = tid & 31;
      float dyn = 0.f;
      const float* s8pp = s8F + h2 * 64 + c * 8;
      const float* mwp = mwgV + tid * 8;
      #pragma unroll
      for (int f = 0; f < 8; f++) dyn += s8pp[f] * mwp[f];
      cl[tid] = (hstatF[h2 * 256 + c * 32 + k2] + dyn) / csumF[h2];
    }
    __syncthreads();
    // fq row
    {
      float a = 0.f;
      const float4* c4 = (const float4*)cl;
      const float4* w4 = (const float4*)(po + (size_t)tid * 256);
      #pragma unroll 4
      for (int e = 0; e < 64; e++) {
        float4 cv = c4[e], wv = w4[e];
        a += cv.x*wv.x + cv.y*wv.y + cv.z*wv.z + cv.w*wv.w;
      }
      fql[tid] = a;
      fqg[(size_t)(b * 8 + c) * 256 + tid] = a;
    }
    __syncthreads();
    {
      int cc2 = tid >> 3, f = tid & 7;
      float s = 0.f;
      for (int d = cc2 * 8; d < cc2 * 8 + 8; d++) s += fql[d] * mwgL[d * 8 + f];
      part[tid] = s;
    }
    __syncthreads();
    if (tid < 8) {
      float s = 0.f;
      for (int cc2 = 0; cc2 < 32; cc2++) s += part[cc2 * 8 + tid];
      lqmg[(b * 8 + c) * 8 + tid] = s;
    }
    __threadfence();
    __syncthreads();
    if (tid == 0) atomicExch(&flag2[b * 8 + c], 1.0f);
  }

  // ---- stage F (all blocks): logits slice of 125 (v,n) for this b ----
  if (tid < 8) spinFlag(&flag2[b * 8 + tid]);
  __threadfence();            // acquire fq/lqm
  __syncthreads();
  float* fqL = U2;            // hstatF dead
  for (int idx = tid; idx < 2048; idx += 256)
    fqL[idx] = fqg[(size_t)b * 2048 + idx];
  if (tid < 64) lqmL[tid] = lqmg[b * 64 + tid];
  __syncthreads();

  {
    int s = blk >> 3;                 // slice 0..63: v = s>>3, n = (s&7)*125+tid
    float ex = 0.f;
    unsigned long long pk = 0ull;
    if (tid < 125) {
      int v = s >> 3;
      int n = (s & 7) * 125 + tid;
      int bvn = (b * 8 + v) * 1000 + n;
      const float4* A  = (const float4*)(fqL + v * 256);
      const float4* Bk = (const float4*)(lKs + ((size_t)(b * 1000 + n)) * 256);
      float dot = 0.f;
      #pragma unroll 8
      for (int d4 = 0; d4 < 64; d4++) {
        float4 x = A[d4], y = Bk[d4];
        dot += x.x*y.x + x.y*y.y + x.z*y.z + x.w*y.w;
      }
      const float4* nd4 = (const float4*)(node_dyn + (size_t)bvn * 8);
      float4 na = nd4[0], nb = nd4[1];
      const float* qm = lqmL + v * 8;
      float dyn = na.x*qm[0] + na.y*qm[1] + na.z*qm[2] + na.w*qm[3]
                + nb.x*qm[4] + nb.y*qm[5] + nb.z*qm[6] + nb.w*qm[7];
      float z = (dot + dyn) * 0.0625f;
      bool on = bytemode ? (((const unsigned char*)maskp)[bvn] != 0)
                         : (((const int*)maskp)[bvn] != 0);
      float L = tanhf(z) * 10.0f + (on ? 0.f : -INFINITY);
      ex = __expf(L);
      unsigned idx = (unsigned)(v * 1000 + n);
      pk = ((unsigned long long)encF(L) << 32) | (unsigned)(~idx);
    }
    float sEx = waveSum(ex);
    unsigned long long mP = waveMaxU(pk);
    if ((tid & 63) == 0) { red4[tid >> 6] = sEx; rP[tid >> 6] = mP; }
    __syncthreads();
    if (tid == 0) {
      float S = red4[0] + red4[1] + red4[2] + red4[3];
      unsigned long long P = rP[0];
      #pragma unroll
      for (int i = 1; i < 4; i++) P = (rP[i] > P) ? rP[i] : P;
      expsum_p[blk] = S;
      packed_p[blk] = P;
      __threadfence();
      atomicExch(&flag3[blk], 1.0f);
    }
  }

  // ---- final: block 0 reduces 512 slots, writes 25 outputs ----
  if (blk == 0) {
    spinFlag(&flag3[tid]);
    spinFlag(&flag3[tid + 256]);
    __threadfence();
    __syncthreads();
    if (tid < 64) {
      float cEnt = 0.f;
      if (tid < 8) {
        float S = 0.f;
        unsigned long long P = 0ull;
        for (int sl = 0; sl < 64; sl++) {
          int j = sl * 8 + tid;
          S += expsum_p[j];
          unsigned long long q = packed_p[j];
          P = (q > P) ? q : P;
        }
        float best = decF((unsigned)(P >> 32));
        unsigned bi = ~(unsigned)(P & 0xffffffffu);
        float logprob = best - logf(S);
        float prob = __expf(logprob);
        out[tid]      = (float)(bi / 1000);
        out[8 + tid]  = (float)(bi % 1000);
        out[16 + tid] = logprob;
        cEnt = prob * logprob;
      }
      cEnt = waveSum(cEnt);
      if (tid == 0) out[24] = -cEnt;
    }
  }
}

extern "C" void kernel_launch(void* const* d_in, const int* in_sizes, int n_in,
                              void* d_out, int out_size, void* d_ws, size_t ws_size,
                              hipStream_t stream) {
  const float* fixedc   = (const float*)d_in[1];
  const float* prev     = (const float*)d_in[2];
  const float* node_dyn = (const float*)d_in[3];
  const float* veh      = (const float*)d_in[4];
  const float* gVs      = (const float*)d_in[5];
  const float* gKs      = (const float*)d_in[6];
  const float* lKs      = (const float*)d_in[7];
  const void*  mask     = d_in[8];
  const float* pcs      = (const float*)d_in[9];
  const float* pns1     = (const float*)d_in[10];
  const float* pns2     = (const float*)d_in[11];
  const float* po       = (const float*)d_in[12];
  float* W   = (float*)d_ws;
  float* out = (float*)d_out;

  fused_all<<<512, 256, 0, stream>>>(node_dyn, gVs, gKs, lKs, mask, fixedc,
                                     prev, veh, pcs, pns1, pns2, po, W, out);
}

// Round 6
// 220.807 us; speedup vs baseline: 1.6586x; 1.6586x over previous
//
#include <hip/hip_runtime.h>
#include <math.h>

// Problem: B=8, V=8, N=1000, D=256, H=8, KS=32
// 3 launches; all cross-block sync at kernel boundaries (rounds 3+5 proved
// intra-kernel grid sync costs 60-100us/sync on MI355X vs ~4us/boundary).
//
// ws float offsets — all partial slots, NO zero-init required.
#define OFF_MWV    0          // Mw rows 0..255   [256*8]
#define OFF_MWL    2048       // Mw rows 512..767 [256*8]
#define OFF_CSUMP  4096       // [512]
#define OFF_HSTATP 4608       // [512*256] -> 135680
#define OFF_S8P    135680     // [512*64]  -> 168448
#define OFF_FQ     168448     // [64*256]  -> 184832
#define OFF_LQM    184832     // [64*8]    -> 185344
#define OFF_EXPSP  185344     // [256]     -> 185600
#define OFF_PACKP  185600     // [256 u64] -> 186112
#define OFF_DONE   186112     // [1] zeroed by k_attn (kernel-boundary release)

__device__ inline float waveSum(float v){
  #pragma unroll
  for (int o = 32; o > 0; o >>= 1) v += __shfl_down(v, o, 64);
  return v;
}
__device__ inline unsigned long long waveMaxU(unsigned long long v){
  #pragma unroll
  for (int o = 32; o > 0; o >>= 1) {
    unsigned long long w = __shfl_down(v, o, 64);
    v = (w > v) ? w : v;
  }
  return v;
}
__device__ inline unsigned encF(float f){
  unsigned u = __float_as_uint(f);
  return (u & 0x80000000u) ? ~u : (u | 0x80000000u);
}
__device__ inline float decF(unsigned u){
  return (u & 0x80000000u) ? __uint_as_float(u & 0x7fffffffu)
                           : __uint_as_float(~u);
}

// ---------------- K_attn: 512 blocks = (h, c, b) ----------------
// Self-contained prep (Mw K-slice, gq, qmk) + compat->exp->partial slots.
__global__ __launch_bounds__(256) void k_attn(
    const float* __restrict__ node_dyn, const float* __restrict__ gVs,
    const float* __restrict__ gKs, const void* __restrict__ maskp,
    const float* __restrict__ fixedc, const float* __restrict__ prev,
    const float* __restrict__ veh, const float* __restrict__ pcs,
    const float* __restrict__ pns1, const float* __restrict__ pns2,
    float* __restrict__ W)
{
  const int blk = blockIdx.x, tid = threadIdx.x;
  const int b = blk & 7, c = (blk >> 3) & 7, h = blk >> 6;
  const int n0 = c * 125;

  float* mwgV    = W + OFF_MWV;
  float* mwgL    = W + OFF_MWL;
  float* csum_p  = W + OFF_CSUMP;
  float* hstat_p = W + OFF_HSTATP;
  float* s8_p    = W + OFF_S8P;

  __shared__ __align__(16) float smemA[2112];   // cvs -> p
  __shared__ __align__(16) float U2[2048];      // Mw partial scratch
  __shared__ __align__(16) float mwk[256];      // K-part Mw rows [32][8]
  __shared__ __align__(16) float gq[256];       // [v][k]
  __shared__ float qmk[64];                     // [v][f]
  __shared__ float red4[4];
  __shared__ int bytemode;

  // mask dtype auto-detect (bool-u8 vs int32)
  if (tid == 0) {
    int bm = 0;
    const unsigned char* mb = (const unsigned char*)maskp;
    for (int idx = 1; idx < 256; idx++)
      if ((idx & 3) != 0 && mb[idx] != 0) { bm = 1; break; }
    bytemode = bm;
  }
  // zero the ticket counter for k_logits (visible via kernel-boundary release)
  if (blk == 16 && tid == 1) ((unsigned*)(W + OFF_DONE))[0] = 0u;

  // stage A0: cvs [8][264]
  for (int idx = tid; idx < 2048; idx += 256) {
    int v = idx >> 8, j = idx & 255;
    smemA[v * 264 + j] = prev[(size_t)(b * 8 + v) * 256 + j];
  }
  if (tid < 64) {
    int v = tid >> 3, j = tid & 7;
    smemA[v * 264 + 256 + j] = veh[(b * 8 + v) * 8 + j];
  }

  // stage A1: Mw rows. set0 = K rows (256+h*32..) -> LDS mwk.
  // (b==0,c==0): also V rows -> global; (b==0,c==1): also L rows -> global.
  {
    int nsets = (b == 0 && c < 2) ? 2 : 1;
    int k = tid >> 3, prt = tid & 7;            // 32 rows x 8 partials
    for (int set = 0; set < nsets; set++) {
      int i0 = (set == 0) ? (256 + h * 32) : ((c == 0) ? h * 32 : 512 + h * 32);
      int i = i0 + k;
      const float* row = pns2 + (size_t)i * 769;
      float acc[7] = {0.f,0.f,0.f,0.f,0.f,0.f,0.f};
      for (int t = 0; t < 96; t++) {
        int j = prt + 8 * t;
        float r = row[j];
        const float* w = pns1 + j * 7;
        #pragma unroll
        for (int f = 0; f < 7; f++) acc[f] += r * w[f];
      }
      __syncthreads();
      #pragma unroll
      for (int f = 0; f < 7; f++) U2[k * 64 + prt * 8 + f] = acc[f];
      __syncthreads();
      int k2 = tid >> 3, f2 = tid & 7;
      int i2 = i0 + k2;
      float val;
      if (f2 < 7) {
        float s = 0.f;
        #pragma unroll
        for (int p2 = 0; p2 < 8; p2++) s += U2[k2 * 64 + p2 * 8 + f2];
        val = pns1[i2 * 7 + f2] + s;
      } else {
        val = pns2[(size_t)i2 * 769 + 768];
      }
      if (set == 0) mwk[k2 * 8 + f2] = val;
      else {
        float* dst = (c == 0) ? (mwgV + (h * 32) * 8) : (mwgL + (h * 32) * 8);
        dst[k2 * 8 + f2] = val;
      }
    }
  }
  __syncthreads();   // cvs + mwk + bytemode ready

  // stage A2: gq[v][k], qmk[v][f]
  {
    int v = tid >> 5, k = tid & 31, d = h * 32 + k;
    float a = fixedc[b * 256 + d];
    const float4* c4 = (const float4*)(smemA + v * 264);
    const float4* w4 = (const float4*)(pcs + (size_t)d * 264);
    #pragma unroll 4
    for (int e = 0; e < 66; e++) {
      float4 cv = c4[e], wv = w4[e];
      a += cv.x*wv.x + cv.y*wv.y + cv.z*wv.z + cv.w*wv.w;
    }
    gq[tid] = a;
  }
  __syncthreads();
  if (tid < 64) {
    int v = tid >> 3, f = tid & 7;
    float a = 0.f;
    for (int k = 0; k < 32; k++) a += gq[v * 32 + k] * mwk[k * 8 + f];
    qmk[tid] = a;
  }
  __syncthreads();   // cvs dead -> smemA reusable as p[1000]

  // stage B: compat -> exp (no max-sub; shift-invariant) -> partial slots
  float* p = smemA;
  float tsum = 0.f;
  for (int e = tid; e < 1000; e += 256) {
    int v = e / 125;
    int n = n0 + (e - v * 125);
    int bvn = (b * 8 + v) * 1000 + n;
    const float4* nd4 = (const float4*)(node_dyn + (size_t)bvn * 8);
    float4 ndA = nd4[0], ndB = nd4[1];
    const float4* gk4 = (const float4*)(gKs + ((size_t)(h * 8 + b) * 1000 + n) * 32);
    const float4* gq4 = (const float4*)(gq + v * 32);
    float s = 0.f;
    #pragma unroll
    for (int k4 = 0; k4 < 8; k4++) {
      float4 g = gk4[k4], q = gq4[k4];
      s += g.x*q.x + g.y*q.y + g.z*q.z + g.w*q.w;
    }
    const float* qm = qmk + v * 8;
    float dyn = ndA.x*qm[0] + ndA.y*qm[1] + ndA.z*qm[2] + ndA.w*qm[3]
              + ndB.x*qm[4] + ndB.y*qm[5] + ndB.z*qm[6] + ndB.w*qm[7];
    bool on = bytemode ? (((const unsigned char*)maskp)[bvn] != 0)
                       : (((const int*)maskp)[bvn] != 0);
    float cc = (s + dyn) * 0.17677669529663687f + (on ? 0.f : -INFINITY);
    float pv = __expf(cc);
    p[e] = pv;
    tsum += pv;
  }
  tsum = waveSum(tsum);
  if ((tid & 63) == 0) red4[tid >> 6] = tsum;
  __syncthreads();
  if (tid == 0) csum_p[blk] = red4[0] + red4[1] + red4[2] + red4[3];
  {
    int v = tid >> 5, k = tid & 31;
    const float* gv = gVs + ((size_t)(h * 8 + b) * 1000 + n0) * 32 + k;
    const float* pr = p + v * 125;
    float a = 0.f;
    #pragma unroll 5
    for (int i = 0; i < 125; i++) a += pr[i] * gv[(size_t)i * 32];
    hstat_p[(size_t)blk * 256 + tid] = a;
  }
  if (tid < 64) {
    int v = tid >> 3, f = tid & 7;
    const float* nd = node_dyn + ((size_t)(b * 8 + v) * 1000 + n0) * 8 + f;
    const float* pr = p + v * 125;
    float a = 0.f;
    #pragma unroll 5
    for (int i = 0; i < 125; i++) a += pr[i] * nd[i * 8];
    s8_p[(size_t)blk * 64 + tid] = a;
  }
}

// ---------------- K_fq: 64 blocks, one (b,v) each ----------------
__global__ __launch_bounds__(256) void k_fq(
    const float* __restrict__ po, float* __restrict__ W)
{
  const int blk = blockIdx.x, tid = threadIdx.x;
  const int b = blk & 7, v = (blk >> 3) & 7;
  const float* mwgV    = W + OFF_MWV;
  const float* mwgL    = W + OFF_MWL;
  const float* csum_p  = W + OFF_CSUMP;
  const float* hstat_p = W + OFF_HSTATP;
  const float* s8_p    = W + OFF_S8P;
  float* fqg = W + OFF_FQ;
  float* lqmg = W + OFF_LQM;

  __shared__ __align__(16) float hstatF[2048];
  __shared__ float csumF[8];
  __shared__ float s8F[512];
  __shared__ __align__(16) float cl[256];
  __shared__ float fql[256];
  __shared__ float part[256];

  for (int h2 = 0; h2 < 8; h2++) {
    float s = 0.f;
    #pragma unroll
    for (int cc = 0; cc < 8; cc++)
      s += hstat_p[(size_t)((h2 << 6) | (cc << 3) | b) * 256 + tid];
    hstatF[h2 * 256 + tid] = s;
  }
  if (tid < 8) {
    float s = 0.f;
    #pragma unroll
    for (int cc = 0; cc < 8; cc++) s += csum_p[(tid << 6) | (cc << 3) | b];
    csumF[tid] = s;
  }
  for (int idx = tid; idx < 512; idx += 256) {
    int h2 = idx >> 6, vf = idx & 63;
    float s = 0.f;
    #pragma unroll
    for (int cc = 0; cc < 8; cc++)
      s += s8_p[(size_t)((h2 << 6) | (cc << 3) | b) * 64 + vf];
    s8F[idx] = s;
  }
  __syncthreads();
  {
    int h2 = tid >> 5, k2 = tid & 31;
    float dyn = 0.f;
    const float* s8pp = s8F + h2 * 64 + v * 8;
    const float* mwp = mwgV + tid * 8;
    #pragma unroll
    for (int f = 0; f < 8; f++) dyn += s8pp[f] * mwp[f];
    cl[tid] = (hstatF[h2 * 256 + v * 32 + k2] + dyn) / csumF[h2];
  }
  __syncthreads();
  {
    float a = 0.f;
    const float4* c4 = (const float4*)cl;
    const float4* w4 = (const float4*)(po + (size_t)tid * 256);
    #pragma unroll 4
    for (int e = 0; e < 64; e++) {
      float4 cv = c4[e], wv = w4[e];
      a += cv.x*wv.x + cv.y*wv.y + cv.z*wv.z + cv.w*wv.w;
    }
    fql[tid] = a;
    fqg[(size_t)(b * 8 + v) * 256 + tid] = a;
  }
  __syncthreads();
  {
    int cc2 = tid >> 3, f = tid & 7;
    float s = 0.f;
    for (int d = cc2 * 8; d < cc2 * 8 + 8; d++) s += fql[d] * mwgL[d * 8 + f];
    part[tid] = s;
  }
  __syncthreads();
  if (tid < 8) {
    float s = 0.f;
    for (int cc2 = 0; cc2 < 32; cc2++) s += part[cc2 * 8 + tid];
    lqmg[(b * 8 + v) * 8 + tid] = s;
  }
}

// ---------------- K_logits: 256 blocks = (b, slice of 32 nodes) ----------------
// logits -> per-block slot (atomicExch) -> ticket last block writes outputs.
__global__ __launch_bounds__(256) void k_logits(
    const float* __restrict__ lKs, const float* __restrict__ node_dyn,
    const void* __restrict__ maskp, float* __restrict__ W,
    float* __restrict__ out)
{
  const int blk = blockIdx.x, tid = threadIdx.x;
  const int b = blk & 7, slice = blk >> 3;
  const int nn = tid >> 3, v = tid & 7;
  const int n = slice * 32 + nn;
  const bool valid = (n < 1000);
  const int n_c = valid ? n : 999;
  const float* fqg  = W + OFF_FQ;
  const float* lqmg = W + OFF_LQM;
  float* expsum_p = W + OFF_EXPSP;
  unsigned long long* packed_p = (unsigned long long*)(W + OFF_PACKP);
  unsigned* done = (unsigned*)(W + OFF_DONE);

  __shared__ float red4[4];
  __shared__ unsigned long long rP[4];
  __shared__ unsigned ticket;
  __shared__ int bytemode;

  if (tid == 0) {
    int bm = 0;
    const unsigned char* mb = (const unsigned char*)maskp;
    for (int idx = 1; idx < 256; idx++)
      if ((idx & 3) != 0 && mb[idx] != 0) { bm = 1; break; }
    bytemode = bm;
  }
  __syncthreads();

  int bvn = (b * 8 + v) * 1000 + n_c;
  const float4* A  = (const float4*)(fqg + (size_t)(b * 8 + v) * 256);
  const float4* Bk = (const float4*)(lKs + ((size_t)(b * 1000 + n_c)) * 256);
  float s = 0.f;
  #pragma unroll 8
  for (int d4 = 0; d4 < 64; d4++) {
    float4 x = A[d4], y = Bk[d4];
    s += x.x*y.x + x.y*y.y + x.z*y.z + x.w*y.w;
  }
  const float4* nd4 = (const float4*)(node_dyn + (size_t)bvn * 8);
  float4 na = nd4[0], nb = nd4[1];
  const float* qm = lqmg + (b * 8 + v) * 8;
  float dyn = na.x*qm[0] + na.y*qm[1] + na.z*qm[2] + na.w*qm[3]
            + nb.x*qm[4] + nb.y*qm[5] + nb.z*qm[6] + nb.w*qm[7];
  float z = (s + dyn) * 0.0625f;
  bool on = bytemode ? (((const unsigned char*)maskp)[bvn] != 0)
                     : (((const int*)maskp)[bvn] != 0);
  float L = tanhf(z) * 10.0f + (on ? 0.f : -INFINITY);
  if (!valid) L = -INFINITY;
  float ex = __expf(L);                     // exp(-inf)=0
  unsigned idx = (unsigned)(v * 1000 + n_c);
  unsigned long long pk = ((unsigned long long)encF(L) << 32) | (unsigned)(~idx);
  float sEx = waveSum(ex);
  unsigned long long mP = waveMaxU(pk);
  if ((tid & 63) == 0) { red4[tid >> 6] = sEx; rP[tid >> 6] = mP; }
  __syncthreads();
  if (tid == 0) {
    float S = red4[0] + red4[1] + red4[2] + red4[3];
    unsigned long long P = rP[0];
    #pragma unroll
    for (int i = 1; i < 4; i++) P = (rP[i] > P) ? rP[i] : P;
    // atomic slot stores -> coherent point (cross-XCD safe)
    atomicExch(&expsum_p[blk], S);
    atomicExch(&packed_p[blk], P);
    __threadfence();
    ticket = atomicAdd(done, 1u);
  }
  __syncthreads();
  if (ticket == 255) {                      // last block: all slots written
    __threadfence();
    if (tid < 64) {
      float cEnt = 0.f;
      if (tid < 8) {
        float S = 0.f;
        unsigned long long P = 0ull;
        for (int sl = 0; sl < 32; sl++) {
          int j = sl * 8 + tid;             // slots of batch tid
          S += atomicAdd(&expsum_p[j], 0.0f);
          unsigned long long q = atomicAdd(&packed_p[j], 0ull);
          P = (q > P) ? q : P;
        }
        float best = decF((unsigned)(P >> 32));
        unsigned bi = ~(unsigned)(P & 0xffffffffu);
        float logprob = best - logf(S);
        float prob = __expf(logprob);
        out[tid]      = (float)(bi / 1000);
        out[8 + tid]  = (float)(bi % 1000);
        out[16 + tid] = logprob;
        cEnt = prob * logprob;
      }
      cEnt = waveSum(cEnt);
      if (tid == 0) out[24] = -cEnt;
    }
  }
}

extern "C" void kernel_launch(void* const* d_in, const int* in_sizes, int n_in,
                              void* d_out, int out_size, void* d_ws, size_t ws_size,
                              hipStream_t stream) {
  const float* fixedc   = (const float*)d_in[1];
  const float* prev     = (const float*)d_in[2];
  const float* node_dyn = (const float*)d_in[3];
  const float* veh      = (const float*)d_in[4];
  const float* gVs      = (const float*)d_in[5];
  const float* gKs      = (const float*)d_in[6];
  const float* lKs      = (const float*)d_in[7];
  const void*  mask     = d_in[8];
  const float* pcs      = (const float*)d_in[9];
  const float* pns1     = (const float*)d_in[10];
  const float* pns2     = (const float*)d_in[11];
  const float* po       = (const float*)d_in[12];
  float* W   = (float*)d_ws;
  float* out = (float*)d_out;

  k_attn<<<512, 256, 0, stream>>>(node_dyn, gVs, gKs, mask, fixedc, prev, veh,
                                  pcs, pns1, pns2, W);
  k_fq<<<64, 256, 0, stream>>>(po, W);
  k_logits<<<256, 256, 0, stream>>>(lKs, node_dyn, mask, W, out);
}

// Round 7
// 203.245 us; speedup vs baseline: 1.8019x; 1.0864x over previous
//
#include <hip/hip_runtime.h>
#include <math.h>

// Problem: B=8, V=8, N=1000, D=256, H=8, KS=32
// 3 launches; all cross-block sync at kernel boundaries (rounds 3+5: any
// intra-kernel cross-XCD sync costs 60-100us vs ~4us per boundary).
// Round-6 lesson: never recompute Mw redundantly / with strided lane access.
//
// ws float offsets — partial-slot handoff, NO zero-init required.
#define OFF_MW     0          // 768*8 = 6144 (rows 0..255 V, 256..511 K, 512..767 L)
#define OFF_QUERY  6144       // 64*256 -> 22528
#define OFF_CSUMP  22528      // [512]      -> 23040
#define OFF_HSTATP 23040      // [512*256]  -> 154112
#define OFF_S8P    154112     // [512*64]   -> 186880
#define OFF_EXPSP  186880     // [64]       -> 186944
#define OFF_PACKP  186944     // [64 u64]   -> 187072  (byte-offset %8 == 0)
#define OFF_DONE   187072     // [1] zeroed by k_prep (kernel-boundary release)

__device__ inline float waveSum(float v){
  #pragma unroll
  for (int o = 32; o > 0; o >>= 1) v += __shfl_down(v, o, 64);
  return v;
}
__device__ inline unsigned long long waveMaxU(unsigned long long v){
  #pragma unroll
  for (int o = 32; o > 0; o >>= 1) {
    unsigned long long w = __shfl_down(v, o, 64);
    v = (w > v) ? w : v;
  }
  return v;
}
__device__ inline unsigned encF(float f){
  unsigned u = __float_as_uint(f);
  return (u & 0x80000000u) ? ~u : (u | 0x80000000u);
}
__device__ inline float decF(unsigned u){
  return (u & 0x80000000u) ? __uint_as_float(u & 0x7fffffffu)
                           : __uint_as_float(~u);
}

// ---------------- K_prep: 832 blocks ----------------
// [0,768): Mw row per block (coalesced);  [768,832): query per (b,v).
__global__ __launch_bounds__(256) void k_prep(
    const float* __restrict__ pns1, const float* __restrict__ pns2,
    const float* __restrict__ prev, const float* __restrict__ veh,
    const float* __restrict__ fixedc, const float* __restrict__ pcs,
    float* __restrict__ W)
{
  int blk = blockIdx.x, tid = threadIdx.x;
  float* mw     = W + OFF_MW;
  float* queryp = W + OFF_QUERY;

  if (blk == 0 && tid == 8) ((unsigned*)(W + OFF_DONE))[0] = 0u;

  if (blk < 768) {
    // Mw[i][f<7] = pns1[i,f] + sum_j pns2[i,j]*pns1[j,f]; Mw[i][7]=pns2[i,768]
    int i = blk;
    __shared__ float red[28];
    const float* row = pns2 + (size_t)i * 769;
    float acc[7] = {0.f,0.f,0.f,0.f,0.f,0.f,0.f};
    #pragma unroll
    for (int t = 0; t < 3; t++) {
      int j = tid + 256 * t;              // lane-contiguous: coalesced
      float r = row[j];
      const float* w = pns1 + j * 7;      // 7 consecutive floats per lane
      #pragma unroll
      for (int f = 0; f < 7; f++) acc[f] += r * w[f];
    }
    #pragma unroll
    for (int f = 0; f < 7; f++) {
      float v = waveSum(acc[f]);
      if ((tid & 63) == 0) red[(tid >> 6) * 7 + f] = v;
    }
    __syncthreads();
    if (tid < 7) {
      float s = red[tid] + red[7 + tid] + red[14 + tid] + red[21 + tid];
      mw[i * 8 + tid] = pns1[i * 7 + tid] + s;
    } else if (tid == 7) {
      mw[i * 8 + 7] = row[768];
    }
  } else {
    int bv = blk - 768;
    __shared__ __align__(16) float cvs[264];
    cvs[tid] = prev[(size_t)bv * 256 + tid];
    if (tid < 8) cvs[256 + tid] = veh[bv * 8 + tid];
    __syncthreads();
    int b = bv >> 3;
    float a = fixedc[b * 256 + tid];
    const float4* c4 = (const float4*)cvs;
    const float4* w4 = (const float4*)(pcs + (size_t)tid * 264);
    #pragma unroll 4
    for (int k = 0; k < 66; k++) {
      float4 cv = c4[k], wv = w4[k];
      a += cv.x*wv.x + cv.y*wv.y + cv.z*wv.z + cv.w*wv.w;
    }
    queryp[(size_t)bv * 256 + tid] = a;
  }
}

// ---------------- K_attn: 512 blocks = (h, c, b) ----------------
// compat -> exp (no max-sub; shift-invariant) -> partial slots (plain stores).
__global__ __launch_bounds__(256) void k_attn(
    const float* __restrict__ node_dyn, const float* __restrict__ gVs,
    const float* __restrict__ gKs, const void* __restrict__ maskp,
    float* __restrict__ W)
{
  const int blk = blockIdx.x, tid = threadIdx.x;
  const int b = blk & 7, c = (blk >> 3) & 7, h = blk >> 6;
  const int n0 = c * 125;
  const float* mw     = W + OFF_MW;
  const float* queryp = W + OFF_QUERY;
  float* csum_p  = W + OFF_CSUMP;
  float* hstat_p = W + OFF_HSTATP;
  float* s8_p    = W + OFF_S8P;

  __shared__ __align__(16) float p[1000];
  __shared__ __align__(16) float gq[256];
  __shared__ float qmk[64];
  __shared__ float red4[4];
  __shared__ int bytemode;

  if (tid == 0) {
    int bm = 0;
    const unsigned char* mb = (const unsigned char*)maskp;
    for (int idx = 1; idx < 256; idx++)
      if ((idx & 3) != 0 && mb[idx] != 0) { bm = 1; break; }
    bytemode = bm;
  }
  gq[tid] = queryp[(size_t)(b * 8 + (tid >> 5)) * 256 + h * 32 + (tid & 31)];
  __syncthreads();
  if (tid < 64) {
    int v = tid >> 3, f = tid & 7;
    float a = 0.f;
    for (int k = 0; k < 32; k++)
      a += gq[v * 32 + k] * mw[(256 + h * 32 + k) * 8 + f];
    qmk[tid] = a;
  }
  __syncthreads();

  float tsum = 0.f;
  for (int e = tid; e < 1000; e += 256) {
    int v = e / 125;
    int n = n0 + (e - v * 125);
    int bvn = (b * 8 + v) * 1000 + n;
    const float4* nd4 = (const float4*)(node_dyn + (size_t)bvn * 8);
    float4 ndA = nd4[0], ndB = nd4[1];
    const float4* gk4 = (const float4*)(gKs + ((size_t)(h * 8 + b) * 1000 + n) * 32);
    const float4* gq4 = (const float4*)(gq + v * 32);
    float s = 0.f;
    #pragma unroll
    for (int k4 = 0; k4 < 8; k4++) {
      float4 g = gk4[k4], q = gq4[k4];
      s += g.x*q.x + g.y*q.y + g.z*q.z + g.w*q.w;
    }
    const float* qm = qmk + v * 8;
    float dyn = ndA.x*qm[0] + ndA.y*qm[1] + ndA.z*qm[2] + ndA.w*qm[3]
              + ndB.x*qm[4] + ndB.y*qm[5] + ndB.z*qm[6] + ndB.w*qm[7];
    bool on = bytemode ? (((const unsigned char*)maskp)[bvn] != 0)
                       : (((const int*)maskp)[bvn] != 0);
    float cc = (s + dyn) * 0.17677669529663687f + (on ? 0.f : -INFINITY);
    float pv = __expf(cc);
    p[e] = pv;
    tsum += pv;
  }
  tsum = waveSum(tsum);
  if ((tid & 63) == 0) red4[tid >> 6] = tsum;
  __syncthreads();
  if (tid == 0) csum_p[blk] = red4[0] + red4[1] + red4[2] + red4[3];
  {
    int v = tid >> 5, k = tid & 31;
    const float* gv = gVs + ((size_t)(h * 8 + b) * 1000 + n0) * 32 + k;
    const float* pr = p + v * 125;
    float a = 0.f;
    #pragma unroll 5
    for (int i = 0; i < 125; i++) a += pr[i] * gv[(size_t)i * 32];
    hstat_p[(size_t)blk * 256 + tid] = a;
  }
  if (tid < 64) {
    int v = tid >> 3, f = tid & 7;
    const float* nd = node_dyn + ((size_t)(b * 8 + v) * 1000 + n0) * 8 + f;
    const float* pr = p + v * 125;
    float a = 0.f;
    #pragma unroll 5
    for (int i = 0; i < 125; i++) a += pr[i] * nd[i * 8];
    s8_p[(size_t)blk * 64 + tid] = a;
  }
}

// ---------------- K_out: 64 blocks = (s=blk>>3 node-slice, b=blk&7) ----------
// reduce partials -> conc -> fq (all 8 v, in-block) -> lqm -> logits(125x8)
// -> per-block slot -> ticket last block writes 25 outputs.
__global__ __launch_bounds__(256) void k_out(
    const float* __restrict__ lKs, const float* __restrict__ node_dyn,
    const void* __restrict__ maskp, const float* __restrict__ po,
    float* __restrict__ W, float* __restrict__ out)
{
  const int blk = blockIdx.x, tid = threadIdx.x;
  const int b = blk & 7, s = blk >> 3;
  const float* mwgV = W + OFF_MW;             // rows 0..255
  const float* mwgL = W + OFF_MW + 512 * 8;   // rows 512..767
  const float* csum_p  = W + OFF_CSUMP;
  const float* hstat_p = W + OFF_HSTATP;
  const float* s8_p    = W + OFF_S8P;
  float* expsum_p = W + OFF_EXPSP;
  unsigned long long* packed_p = (unsigned long long*)(W + OFF_PACKP);
  unsigned* done = (unsigned*)(W + OFF_DONE);

  __shared__ __align__(16) float hstatF[2048];   // [h][v*32+k]
  __shared__ float csumF[8];
  __shared__ float s8F[512];                     // [h][v*8+f]
  __shared__ __align__(16) float clF[2048];      // [v][256]
  __shared__ __align__(16) float fqL[8 * 260];   // [v][260] pad->bank-safe
  __shared__ float lqmL[64];
  __shared__ float red4[4];
  __shared__ unsigned long long rP[4];
  __shared__ unsigned ticket;
  __shared__ int bytemode;

  if (tid == 0) {
    int bm = 0;
    const unsigned char* mb = (const unsigned char*)maskp;
    for (int idx = 1; idx < 256; idx++)
      if ((idx & 3) != 0 && mb[idx] != 0) { bm = 1; break; }
    bytemode = bm;
  }

  // stage 1: reduce 8 c-slots per (h,b)
  for (int h2 = 0; h2 < 8; h2++) {
    float sum = 0.f;
    #pragma unroll
    for (int cc = 0; cc < 8; cc++)
      sum += hstat_p[(size_t)((h2 << 6) | (cc << 3) | b) * 256 + tid];
    hstatF[h2 * 256 + tid] = sum;
  }
  if (tid < 8) {
    float sum = 0.f;
    #pragma unroll
    for (int cc = 0; cc < 8; cc++) sum += csum_p[(tid << 6) | (cc << 3) | b];
    csumF[tid] = sum;
  }
  for (int idx = tid; idx < 512; idx += 256) {
    int h2 = idx >> 6, vf = idx & 63;
    float sum = 0.f;
    #pragma unroll
    for (int cc = 0; cc < 8; cc++)
      sum += s8_p[(size_t)((h2 << 6) | (cc << 3) | b) * 64 + vf];
    s8F[idx] = sum;
  }
  __syncthreads();

  // stage 2: conc for all 8 v (d = tid)
  {
    int h2 = tid >> 5, k2 = tid & 31;
    float mwp[8];
    #pragma unroll
    for (int f = 0; f < 8; f++) mwp[f] = mwgV[tid * 8 + f];
    float rinv = 1.0f / csumF[h2];
    #pragma unroll
    for (int v = 0; v < 8; v++) {
      float dyn = 0.f;
      const float* s8v = s8F + h2 * 64 + v * 8;
      #pragma unroll
      for (int f = 0; f < 8; f++) dyn += s8v[f] * mwp[f];
      clF[v * 256 + tid] = (hstatF[h2 * 256 + v * 32 + k2] + dyn) * rinv;
    }
  }
  __syncthreads();

  // stage 3: fq[v][tid] = cl[v] . po[tid]  (po row in float4, cl broadcast)
  {
    float acc[8] = {0.f,0.f,0.f,0.f,0.f,0.f,0.f,0.f};
    const float4* w4 = (const float4*)(po + (size_t)tid * 256);
    const float4* c4 = (const float4*)clF;
    for (int e4 = 0; e4 < 64; e4++) {
      float4 wv = w4[e4];
      #pragma unroll
      for (int v = 0; v < 8; v++) {
        float4 cv = c4[v * 64 + e4];
        acc[v] += cv.x*wv.x + cv.y*wv.y + cv.z*wv.z + cv.w*wv.w;
      }
    }
    #pragma unroll
    for (int v = 0; v < 8; v++) fqL[v * 260 + tid] = acc[v];
  }
  __syncthreads();

  // stage 4: lqm[v][f] = sum_d fq[v][d] * MwL[d][f]
  if (tid < 64) {
    int v = tid >> 3, f = tid & 7;
    float sum = 0.f;
    for (int d = 0; d < 256; d++) sum += fqL[v * 260 + d] * mwgL[d * 8 + f];
    lqmL[tid] = sum;
  }
  __syncthreads();

  // stage 5: logits for 125 n x 8 v; 4 rounds of (nn=tid>>3, v=tid&7)
  float exAcc = 0.f;
  unsigned long long pkMax = 0ull;
  #pragma unroll
  for (int r = 0; r < 4; r++) {
    int nl = r * 32 + (tid >> 3), v = tid & 7;
    bool valid = (nl < 125);
    int nlc = valid ? nl : 124;
    int n = s * 125 + nlc;
    int bvn = (b * 8 + v) * 1000 + n;
    const float4* A  = (const float4*)(fqL + v * 260);
    const float4* Bk = (const float4*)(lKs + ((size_t)(b * 1000 + n)) * 256);
    float dot = 0.f;
    #pragma unroll 8
    for (int d4 = 0; d4 < 64; d4++) {
      float4 x = A[d4], y = Bk[d4];
      dot += x.x*y.x + x.y*y.y + x.z*y.z + x.w*y.w;
    }
    const float4* nd4 = (const float4*)(node_dyn + (size_t)bvn * 8);
    float4 na = nd4[0], nb = nd4[1];
    const float* qm = lqmL + v * 8;
    float dyn = na.x*qm[0] + na.y*qm[1] + na.z*qm[2] + na.w*qm[3]
              + nb.x*qm[4] + nb.y*qm[5] + nb.z*qm[6] + nb.w*qm[7];
    float z = (dot + dyn) * 0.0625f;
    bool on = bytemode ? (((const unsigned char*)maskp)[bvn] != 0)
                       : (((const int*)maskp)[bvn] != 0);
    float L = tanhf(z) * 10.0f + (on ? 0.f : -INFINITY);
    if (!valid) L = -INFINITY;
    exAcc += __expf(L);                       // exp(-inf)=0
    unsigned idx = (unsigned)(v * 1000 + n);
    unsigned long long pk = ((unsigned long long)encF(L) << 32) | (unsigned)(~idx);
    pkMax = (pk > pkMax) ? pk : pkMax;
  }
  float sEx = waveSum(exAcc);
  unsigned long long mP = waveMaxU(pkMax);
  if ((tid & 63) == 0) { red4[tid >> 6] = sEx; rP[tid >> 6] = mP; }
  __syncthreads();
  if (tid == 0) {
    float S = red4[0] + red4[1] + red4[2] + red4[3];
    unsigned long long P = rP[0];
    #pragma unroll
    for (int i = 1; i < 4; i++) P = (rP[i] > P) ? rP[i] : P;
    atomicExch(&expsum_p[blk], S);            // coherent-point slot stores
    atomicExch(&packed_p[blk], P);
    __threadfence();
    ticket = atomicAdd(done, 1u);
  }
  __syncthreads();
  if (ticket == 63) {                         // last block: all slots written
    __threadfence();
    if (tid < 64) {
      float cEnt = 0.f;
      if (tid < 8) {
        float S = 0.f;
        unsigned long long P = 0ull;
        for (int sl = 0; sl < 8; sl++) {
          int j = sl * 8 + tid;               // slots of batch tid
          S += atomicAdd(&expsum_p[j], 0.0f);
          unsigned long long q = atomicAdd(&packed_p[j], 0ull);
          P = (q > P) ? q : P;
        }
        float best = decF((unsigned)(P >> 32));
        unsigned bi = ~(unsigned)(P & 0xffffffffu);
        float logprob = best - logf(S);
        float prob = __expf(logprob);
        out[tid]      = (float)(bi / 1000);
        out[8 + tid]  = (float)(bi % 1000);
        out[16 + tid] = logprob;
        cEnt = prob * logprob;
      }
      cEnt = waveSum(cEnt);
      if (tid == 0) out[24] = -cEnt;
    }
  }
}

extern "C" void kernel_launch(void* const* d_in, const int* in_sizes, int n_in,
                              void* d_out, int out_size, void* d_ws, size_t ws_size,
                              hipStream_t stream) {
  const float* fixedc   = (const float*)d_in[1];
  const float* prev     = (const float*)d_in[2];
  const float* node_dyn = (const float*)d_in[3];
  const float* veh      = (const float*)d_in[4];
  const float* gVs      = (const float*)d_in[5];
  const float* gKs      = (const float*)d_in[6];
  const float* lKs      = (const float*)d_in[7];
  const void*  mask     = d_in[8];
  const float* pcs      = (const float*)d_in[9];
  const float* pns1     = (const float*)d_in[10];
  const float* pns2     = (const float*)d_in[11];
  const float* po       = (const float*)d_in[12];
  float* W   = (float*)d_ws;
  float* out = (float*)d_out;

  k_prep<<<832, 256, 0, stream>>>(pns1, pns2, prev, veh, fixedc, pcs, W);
  k_attn<<<512, 256, 0, stream>>>(node_dyn, gVs, gKs, mask, W);
  k_out<<<64, 256, 0, stream>>>(lKs, node_dyn, mask, po, W, out);
}

// Round 8
// 198.648 us; speedup vs baseline: 1.8436x; 1.0231x over previous
//
#include <hip/hip_runtime.h>
#include <math.h>

// Problem: B=8, V=8, N=1000, D=256, H=8, KS=32
// 4 launches. Rules learned r3-r7: sync ONLY at kernel boundaries (~4us each;
// intra-kernel cross-XCD sync = 60-100us); never run a phase at <256 blocks
// if it has serial stages (r7 k_out: 66us at 2.5% occupancy); never recompute
// Mw redundantly with strided lane access (r6 k_attn: 88us).
//
// ws float offsets — partial-slot handoff, NO zero-init required.
#define OFF_MW     0          // 768*8 = 6144 (rows 0..255 V, 256..511 K, 512..767 L)
#define OFF_QUERY  6144       // 64*256 -> 22528
#define OFF_CSUMP  22528      // [512]      -> 23040
#define OFF_HSTATP 23040      // [512*256]  -> 154112
#define OFF_S8P    154112     // [512*64]   -> 186880
#define OFF_FQ     186880     // [64*256]   -> 203264
#define OFF_LQM    203264     // [64*8]     -> 203776
#define OFF_EXPSP  203776     // [256]      -> 204032
#define OFF_PACKP  204032     // [256 u64]  -> 204544 (byte-offset %8 == 0)
#define OFF_DONE   204544     // [1] zeroed by k_prep (kernel-boundary release)

__device__ inline float waveSum(float v){
  #pragma unroll
  for (int o = 32; o > 0; o >>= 1) v += __shfl_down(v, o, 64);
  return v;
}
__device__ inline unsigned long long waveMaxU(unsigned long long v){
  #pragma unroll
  for (int o = 32; o > 0; o >>= 1) {
    unsigned long long w = __shfl_down(v, o, 64);
    v = (w > v) ? w : v;
  }
  return v;
}
__device__ inline unsigned encF(float f){
  unsigned u = __float_as_uint(f);
  return (u & 0x80000000u) ? ~u : (u | 0x80000000u);
}
__device__ inline float decF(unsigned u){
  return (u & 0x80000000u) ? __uint_as_float(u & 0x7fffffffu)
                           : __uint_as_float(~u);
}

// ---------------- K_prep: 832 blocks ----------------
// [0,768): Mw row per block (coalesced);  [768,832): query per (b,v).
__global__ __launch_bounds__(256) void k_prep(
    const float* __restrict__ pns1, const float* __restrict__ pns2,
    const float* __restrict__ prev, const float* __restrict__ veh,
    const float* __restrict__ fixedc, const float* __restrict__ pcs,
    float* __restrict__ W)
{
  int blk = blockIdx.x, tid = threadIdx.x;
  float* mw     = W + OFF_MW;
  float* queryp = W + OFF_QUERY;

  if (blk == 0 && tid == 8) ((unsigned*)(W + OFF_DONE))[0] = 0u;

  if (blk < 768) {
    // Mw[i][f<7] = pns1[i,f] + sum_j pns2[i,j]*pns1[j,f]; Mw[i][7]=pns2[i,768]
    int i = blk;
    __shared__ float red[28];
    const float* row = pns2 + (size_t)i * 769;
    float acc[7] = {0.f,0.f,0.f,0.f,0.f,0.f,0.f};
    #pragma unroll
    for (int t = 0; t < 3; t++) {
      int j = tid + 256 * t;              // lane-contiguous: coalesced
      float r = row[j];
      const float* w = pns1 + j * 7;
      #pragma unroll
      for (int f = 0; f < 7; f++) acc[f] += r * w[f];
    }
    #pragma unroll
    for (int f = 0; f < 7; f++) {
      float v = waveSum(acc[f]);
      if ((tid & 63) == 0) red[(tid >> 6) * 7 + f] = v;
    }
    __syncthreads();
    if (tid < 7) {
      float s = red[tid] + red[7 + tid] + red[14 + tid] + red[21 + tid];
      mw[i * 8 + tid] = pns1[i * 7 + tid] + s;
    } else if (tid == 7) {
      mw[i * 8 + 7] = row[768];
    }
  } else {
    int bv = blk - 768;
    __shared__ __align__(16) float cvs[264];
    cvs[tid] = prev[(size_t)bv * 256 + tid];
    if (tid < 8) cvs[256 + tid] = veh[bv * 8 + tid];
    __syncthreads();
    int b = bv >> 3;
    float a = fixedc[b * 256 + tid];
    const float4* c4 = (const float4*)cvs;
    const float4* w4 = (const float4*)(pcs + (size_t)tid * 264);
    #pragma unroll 4
    for (int k = 0; k < 66; k++) {
      float4 cv = c4[k], wv = w4[k];
      a += cv.x*wv.x + cv.y*wv.y + cv.z*wv.z + cv.w*wv.w;
    }
    queryp[(size_t)bv * 256 + tid] = a;
  }
}

// ---------------- K_attn: 512 blocks = (h, c, b) ----------------
// compat -> exp (no max-sub; shift-invariant) -> partial slots (plain stores).
__global__ __launch_bounds__(256) void k_attn(
    const float* __restrict__ node_dyn, const float* __restrict__ gVs,
    const float* __restrict__ gKs, const void* __restrict__ maskp,
    float* __restrict__ W)
{
  const int blk = blockIdx.x, tid = threadIdx.x;
  const int b = blk & 7, c = (blk >> 3) & 7, h = blk >> 6;
  const int n0 = c * 125;
  const float* mw     = W + OFF_MW;
  const float* queryp = W + OFF_QUERY;
  float* csum_p  = W + OFF_CSUMP;
  float* hstat_p = W + OFF_HSTATP;
  float* s8_p    = W + OFF_S8P;

  __shared__ __align__(16) float p[1000];
  __shared__ __align__(16) float gq[256];
  __shared__ float qmk[64];
  __shared__ float red4[4];
  __shared__ int bytemode;

  if (tid == 0) {
    int bm = 0;
    const unsigned char* mb = (const unsigned char*)maskp;
    for (int idx = 1; idx < 256; idx++)
      if ((idx & 3) != 0 && mb[idx] != 0) { bm = 1; break; }
    bytemode = bm;
  }
  gq[tid] = queryp[(size_t)(b * 8 + (tid >> 5)) * 256 + h * 32 + (tid & 31)];
  __syncthreads();
  if (tid < 64) {
    int v = tid >> 3, f = tid & 7;
    float a = 0.f;
    for (int k = 0; k < 32; k++)
      a += gq[v * 32 + k] * mw[(256 + h * 32 + k) * 8 + f];
    qmk[tid] = a;
  }
  __syncthreads();

  float tsum = 0.f;
  for (int e = tid; e < 1000; e += 256) {
    int v = e / 125;
    int n = n0 + (e - v * 125);
    int bvn = (b * 8 + v) * 1000 + n;
    const float4* nd4 = (const float4*)(node_dyn + (size_t)bvn * 8);
    float4 ndA = nd4[0], ndB = nd4[1];
    const float4* gk4 = (const float4*)(gKs + ((size_t)(h * 8 + b) * 1000 + n) * 32);
    const float4* gq4 = (const float4*)(gq + v * 32);
    float s = 0.f;
    #pragma unroll
    for (int k4 = 0; k4 < 8; k4++) {
      float4 g = gk4[k4], q = gq4[k4];
      s += g.x*q.x + g.y*q.y + g.z*q.z + g.w*q.w;
    }
    const float* qm = qmk + v * 8;
    float dyn = ndA.x*qm[0] + ndA.y*qm[1] + ndA.z*qm[2] + ndA.w*qm[3]
              + ndB.x*qm[4] + ndB.y*qm[5] + ndB.z*qm[6] + ndB.w*qm[7];
    bool on = bytemode ? (((const unsigned char*)maskp)[bvn] != 0)
                       : (((const int*)maskp)[bvn] != 0);
    float cc = (s + dyn) * 0.17677669529663687f + (on ? 0.f : -INFINITY);
    float pv = __expf(cc);
    p[e] = pv;
    tsum += pv;
  }
  tsum = waveSum(tsum);
  if ((tid & 63) == 0) red4[tid >> 6] = tsum;
  __syncthreads();
  if (tid == 0) csum_p[blk] = red4[0] + red4[1] + red4[2] + red4[3];
  {
    int v = tid >> 5, k = tid & 31;
    const float* gv = gVs + ((size_t)(h * 8 + b) * 1000 + n0) * 32 + k;
    const float* pr = p + v * 125;
    float a = 0.f;
    #pragma unroll 5
    for (int i = 0; i < 125; i++) a += pr[i] * gv[(size_t)i * 32];
    hstat_p[(size_t)blk * 256 + tid] = a;
  }
  if (tid < 64) {
    int v = tid >> 3, f = tid & 7;
    const float* nd = node_dyn + ((size_t)(b * 8 + v) * 1000 + n0) * 8 + f;
    const float* pr = p + v * 125;
    float a = 0.f;
    #pragma unroll 5
    for (int i = 0; i < 125; i++) a += pr[i] * nd[i * 8];
    s8_p[(size_t)blk * 64 + tid] = a;
  }
}

// ---------------- K_fq: 64 blocks, one (b,v) each ----------------
// reduce partial slots -> conc -> fq -> lqm (to global).
__global__ __launch_bounds__(256) void k_fq(
    const float* __restrict__ po, float* __restrict__ W)
{
  const int blk = blockIdx.x, tid = threadIdx.x;
  const int b = blk & 7, v = (blk >> 3) & 7;
  const float* mwgV    = W + OFF_MW;            // rows 0..255
  const float* mwgL    = W + OFF_MW + 512 * 8;  // rows 512..767
  const float* csum_p  = W + OFF_CSUMP;
  const float* hstat_p = W + OFF_HSTATP;
  const float* s8_p    = W + OFF_S8P;
  float* fqg  = W + OFF_FQ;
  float* lqmg = W + OFF_LQM;

  __shared__ __align__(16) float hstatF[2048];
  __shared__ float csumF[8];
  __shared__ float s8F[512];
  __shared__ __align__(16) float cl[256];
  __shared__ float fql[256];
  __shared__ float part[256];

  for (int h2 = 0; h2 < 8; h2++) {
    float s = 0.f;
    #pragma unroll
    for (int cc = 0; cc < 8; cc++)
      s += hstat_p[(size_t)((h2 << 6) | (cc << 3) | b) * 256 + tid];
    hstatF[h2 * 256 + tid] = s;
  }
  if (tid < 8) {
    float s = 0.f;
    #pragma unroll
    for (int cc = 0; cc < 8; cc++) s += csum_p[(tid << 6) | (cc << 3) | b];
    csumF[tid] = s;
  }
  for (int idx = tid; idx < 512; idx += 256) {
    int h2 = idx >> 6, vf = idx & 63;
    float s = 0.f;
    #pragma unroll
    for (int cc = 0; cc < 8; cc++)
      s += s8_p[(size_t)((h2 << 6) | (cc << 3) | b) * 64 + vf];
    s8F[idx] = s;
  }
  __syncthreads();
  {
    int h2 = tid >> 5, k2 = tid & 31;
    float dyn = 0.f;
    const float* s8pp = s8F + h2 * 64 + v * 8;
    const float* mwp = mwgV + tid * 8;
    #pragma unroll
    for (int f = 0; f < 8; f++) dyn += s8pp[f] * mwp[f];
    cl[tid] = (hstatF[h2 * 256 + v * 32 + k2] + dyn) / csumF[h2];
  }
  __syncthreads();
  {
    float a = 0.f;
    const float4* c4 = (const float4*)cl;
    const float4* w4 = (const float4*)(po + (size_t)tid * 256);
    #pragma unroll 4
    for (int e = 0; e < 64; e++) {
      float4 cv = c4[e], wv = w4[e];
      a += cv.x*wv.x + cv.y*wv.y + cv.z*wv.z + cv.w*wv.w;
    }
    fql[tid] = a;
    fqg[(size_t)(b * 8 + v) * 256 + tid] = a;
  }
  __syncthreads();
  {
    int cc2 = tid >> 3, f = tid & 7;
    float s = 0.f;
    for (int d = cc2 * 8; d < cc2 * 8 + 8; d++) s += fql[d] * mwgL[d * 8 + f];
    part[tid] = s;
  }
  __syncthreads();
  if (tid < 8) {
    float s = 0.f;
    for (int cc2 = 0; cc2 < 32; cc2++) s += part[cc2 * 8 + tid];
    lqmg[(b * 8 + v) * 8 + tid] = s;
  }
}

// ---------------- K_logits: 256 blocks = (b, slice of 32 nodes) -------------
// one (v,n) dot per thread -> per-block slot -> ticket last block -> outputs.
__global__ __launch_bounds__(256) void k_logits(
    const float* __restrict__ lKs, const float* __restrict__ node_dyn,
    const void* __restrict__ maskp, float* __restrict__ W,
    float* __restrict__ out)
{
  const int blk = blockIdx.x, tid = threadIdx.x;
  const int b = blk & 7, slice = blk >> 3;
  const int nn = tid >> 3, v = tid & 7;
  const int n = slice * 32 + nn;
  const bool valid = (n < 1000);
  const int n_c = valid ? n : 999;
  const float* fqg  = W + OFF_FQ;
  const float* lqmg = W + OFF_LQM;
  float* expsum_p = W + OFF_EXPSP;
  unsigned long long* packed_p = (unsigned long long*)(W + OFF_PACKP);
  unsigned* done = (unsigned*)(W + OFF_DONE);

  __shared__ float red4[4];
  __shared__ unsigned long long rP[4];
  __shared__ unsigned ticket;
  __shared__ int bytemode;

  if (tid == 0) {
    int bm = 0;
    const unsigned char* mb = (const unsigned char*)maskp;
    for (int idx = 1; idx < 256; idx++)
      if ((idx & 3) != 0 && mb[idx] != 0) { bm = 1; break; }
    bytemode = bm;
  }
  __syncthreads();

  int bvn = (b * 8 + v) * 1000 + n_c;
  const float4* A  = (const float4*)(fqg + (size_t)(b * 8 + v) * 256);
  const float4* Bk = (const float4*)(lKs + ((size_t)(b * 1000 + n_c)) * 256);
  float s = 0.f;
  #pragma unroll 8
  for (int d4 = 0; d4 < 64; d4++) {
    float4 x = A[d4], y = Bk[d4];
    s += x.x*y.x + x.y*y.y + x.z*y.z + x.w*y.w;
  }
  const float4* nd4 = (const float4*)(node_dyn + (size_t)bvn * 8);
  float4 na = nd4[0], nb = nd4[1];
  const float* qm = lqmg + (b * 8 + v) * 8;
  float dyn = na.x*qm[0] + na.y*qm[1] + na.z*qm[2] + na.w*qm[3]
            + nb.x*qm[4] + nb.y*qm[5] + nb.z*qm[6] + nb.w*qm[7];
  float z = (s + dyn) * 0.0625f;
  bool on = bytemode ? (((const unsigned char*)maskp)[bvn] != 0)
                     : (((const int*)maskp)[bvn] != 0);
  float L = tanhf(z) * 10.0f + (on ? 0.f : -INFINITY);
  if (!valid) L = -INFINITY;
  float ex = __expf(L);                     // exp(-inf)=0
  unsigned idx = (unsigned)(v * 1000 + n_c);
  unsigned long long pk = ((unsigned long long)encF(L) << 32) | (unsigned)(~idx);
  float sEx = waveSum(ex);
  unsigned long long mP = waveMaxU(pk);
  if ((tid & 63) == 0) { red4[tid >> 6] = sEx; rP[tid >> 6] = mP; }
  __syncthreads();
  if (tid == 0) {
    float S = red4[0] + red4[1] + red4[2] + red4[3];
    unsigned long long P = rP[0];
    #pragma unroll
    for (int i = 1; i < 4; i++) P = (rP[i] > P) ? rP[i] : P;
    atomicExch(&expsum_p[blk], S);          // coherent-point slot stores
    atomicExch(&packed_p[blk], P);
    __threadfence();
    ticket = atomicAdd(done, 1u);
  }
  __syncthreads();
  if (ticket == 255) {                      // last block: all slots written
    __threadfence();
    if (tid < 64) {
      float cEnt = 0.f;
      if (tid < 8) {
        float S = 0.f;
        unsigned long long P = 0ull;
        for (int sl = 0; sl < 32; sl++) {
          int j = sl * 8 + tid;             // slots of batch tid
          S += atomicAdd(&expsum_p[j], 0.0f);
          unsigned long long q = atomicAdd(&packed_p[j], 0ull);
          P = (q > P) ? q : P;
        }
        float best = decF((unsigned)(P >> 32));
        unsigned bi = ~(unsigned)(P & 0xffffffffu);
        float logprob = best - logf(S);
        float prob = __expf(logprob);
        out[tid]      = (float)(bi / 1000);
        out[8 + tid]  = (float)(bi % 1000);
        out[16 + tid] = logprob;
        cEnt = prob * logprob;
      }
      cEnt = waveSum(cEnt);
      if (tid == 0) out[24] = -cEnt;
    }
  }
}

extern "C" void kernel_launch(void* const* d_in, const int* in_sizes, int n_in,
                              void* d_out, int out_size, void* d_ws, size_t ws_size,
                              hipStream_t stream) {
  const float* fixedc   = (const float*)d_in[1];
  const float* prev     = (const float*)d_in[2];
  const float* node_dyn = (const float*)d_in[3];
  const float* veh      = (const float*)d_in[4];
  const float* gVs      = (const float*)d_in[5];
  const float* gKs      = (const float*)d_in[6];
  const float* lKs      = (const float*)d_in[7];
  const void*  mask     = d_in[8];
  const float* pcs      = (const float*)d_in[9];
  const float* pns1     = (const float*)d_in[10];
  const float* pns2     = (const float*)d_in[11];
  const float* po       = (const float*)d_in[12];
  float* W   = (float*)d_ws;
  float* out = (float*)d_out;

  k_prep<<<832, 256, 0, stream>>>(pns1, pns2, prev, veh, fixedc, pcs, W);
  k_attn<<<512, 256, 0, stream>>>(node_dyn, gVs, gKs, mask, W);
  k_fq<<<64, 256, 0, stream>>>(po, W);
  k_logits<<<256, 256, 0, stream>>>(lKs, node_dyn, mask, W, out);
}

// Round 9
// 160.201 us; speedup vs baseline: 2.2860x; 1.2400x over previous
//
#include <hip/hip_runtime.h>
#include <math.h>

// Problem: B=8, V=8, N=1000, D=256, H=8, KS=32
// 4 launches. Rules learned r3-r8: sync ONLY at kernel boundaries (~4us each;
// intra-kernel cross-XCD sync = 60-100us); keep every phase >=256 blocks wide
// (r7 k_out: 66us at 2.5% occupancy); never recompute Mw redundantly with
// strided lane access (r6: 88us); NEVER serial-probe global memory from one
// thread (r8: ~25us of dependent byte loads stalled every block).
//
// ws float offsets — partial-slot handoff, NO zero-init required.
#define OFF_MW     0          // 768*8 = 6144 (rows 0..255 V, 256..511 K, 512..767 L)
#define OFF_QUERY  6144       // 64*256 -> 22528
#define OFF_CSUMP  22528      // [512]      -> 23040
#define OFF_HSTATP 23040      // [512*256]  -> 154112
#define OFF_S8P    154112     // [512*64]   -> 186880
#define OFF_FQ     186880     // [64*256]   -> 203264
#define OFF_LQM    203264     // [64*8]     -> 203776
#define OFF_EXPSP  203776     // [256]      -> 204032
#define OFF_PACKP  204032     // [256 u64]  -> 204544 (byte-offset %8 == 0)
#define OFF_DONE   204544     // [1] zeroed by k_prep (kernel-boundary release)

__device__ inline float waveSum(float v){
  #pragma unroll
  for (int o = 32; o > 0; o >>= 1) v += __shfl_down(v, o, 64);
  return v;
}
__device__ inline unsigned long long waveMaxU(unsigned long long v){
  #pragma unroll
  for (int o = 32; o > 0; o >>= 1) {
    unsigned long long w = __shfl_down(v, o, 64);
    v = (w > v) ? w : v;
  }
  return v;
}
__device__ inline unsigned encF(float f){
  unsigned u = __float_as_uint(f);
  return (u & 0x80000000u) ? ~u : (u | 0x80000000u);
}
__device__ inline float decF(unsigned u){
  return (u & 0x80000000u) ? __uint_as_float(u & 0x7fffffffu)
                           : __uint_as_float(~u);
}

// Parallel mask-dtype probe: 256 threads, one byte each, ballot + wave-OR.
// (int32 bool: bytes at idx%4!=0 are all zero; u8 bool: ~70% nonzero.)
__device__ inline int probeByteMode(const void* maskp, int tid, int* bmShared){
  const unsigned char* mb = (const unsigned char*)maskp;
  bool hit = (tid > 0) && ((tid & 3) != 0) && (mb[tid] != 0);
  unsigned long long bal = __ballot(hit);
  if (tid == 0) *bmShared = 0;
  __syncthreads();
  if ((tid & 63) == 0 && bal != 0ull) *bmShared = 1;
  __syncthreads();
  return *bmShared;
}

// ---------------- K_prep: 832 blocks ----------------
// [0,768): Mw row per block (coalesced);  [768,832): query per (b,v).
__global__ __launch_bounds__(256) void k_prep(
    const float* __restrict__ pns1, const float* __restrict__ pns2,
    const float* __restrict__ prev, const float* __restrict__ veh,
    const float* __restrict__ fixedc, const float* __restrict__ pcs,
    float* __restrict__ W)
{
  int blk = blockIdx.x, tid = threadIdx.x;
  float* mw     = W + OFF_MW;
  float* queryp = W + OFF_QUERY;

  if (blk == 0 && tid == 8) ((unsigned*)(W + OFF_DONE))[0] = 0u;

  if (blk < 768) {
    // Mw[i][f<7] = pns1[i,f] + sum_j pns2[i,j]*pns1[j,f]; Mw[i][7]=pns2[i,768]
    int i = blk;
    __shared__ float red[28];
    const float* row = pns2 + (size_t)i * 769;
    float acc[7] = {0.f,0.f,0.f,0.f,0.f,0.f,0.f};
    #pragma unroll
    for (int t = 0; t < 3; t++) {
      int j = tid + 256 * t;              // lane-contiguous: coalesced
      float r = row[j];
      const float* w = pns1 + j * 7;
      #pragma unroll
      for (int f = 0; f < 7; f++) acc[f] += r * w[f];
    }
    #pragma unroll
    for (int f = 0; f < 7; f++) {
      float v = waveSum(acc[f]);
      if ((tid & 63) == 0) red[(tid >> 6) * 7 + f] = v;
    }
    __syncthreads();
    if (tid < 7) {
      float s = red[tid] + red[7 + tid] + red[14 + tid] + red[21 + tid];
      mw[i * 8 + tid] = pns1[i * 7 + tid] + s;
    } else if (tid == 7) {
      mw[i * 8 + 7] = row[768];
    }
  } else {
    int bv = blk - 768;
    __shared__ __align__(16) float cvs[264];
    cvs[tid] = prev[(size_t)bv * 256 + tid];
    if (tid < 8) cvs[256 + tid] = veh[bv * 8 + tid];
    __syncthreads();
    int b = bv >> 3;
    float a = fixedc[b * 256 + tid];
    const float4* c4 = (const float4*)cvs;
    const float4* w4 = (const float4*)(pcs + (size_t)tid * 264);
    #pragma unroll 4
    for (int k = 0; k < 66; k++) {
      float4 cv = c4[k], wv = w4[k];
      a += cv.x*wv.x + cv.y*wv.y + cv.z*wv.z + cv.w*wv.w;
    }
    queryp[(size_t)bv * 256 + tid] = a;
  }
}

// ---------------- K_attn: 512 blocks = (h, c, b) ----------------
// compat -> exp (no max-sub; shift-invariant) -> partial slots (plain stores).
__global__ __launch_bounds__(256) void k_attn(
    const float* __restrict__ node_dyn, const float* __restrict__ gVs,
    const float* __restrict__ gKs, const void* __restrict__ maskp,
    float* __restrict__ W)
{
  const int blk = blockIdx.x, tid = threadIdx.x;
  const int b = blk & 7, c = (blk >> 3) & 7, h = blk >> 6;
  const int n0 = c * 125;
  const float* mw     = W + OFF_MW;
  const float* queryp = W + OFF_QUERY;
  float* csum_p  = W + OFF_CSUMP;
  float* hstat_p = W + OFF_HSTATP;
  float* s8_p    = W + OFF_S8P;

  __shared__ __align__(16) float p[1000];
  __shared__ __align__(16) float gq[256];
  __shared__ float qmk[64];
  __shared__ float red4[4];
  __shared__ int bmS;

  gq[tid] = queryp[(size_t)(b * 8 + (tid >> 5)) * 256 + h * 32 + (tid & 31)];
  int bytemode = probeByteMode(maskp, tid, &bmS);   // includes 2 barriers
  if (tid < 64) {
    int v = tid >> 3, f = tid & 7;
    float a = 0.f;
    for (int k = 0; k < 32; k++)
      a += gq[v * 32 + k] * mw[(256 + h * 32 + k) * 8 + f];
    qmk[tid] = a;
  }
  __syncthreads();

  float tsum = 0.f;
  for (int e = tid; e < 1000; e += 256) {
    int v = e / 125;
    int n = n0 + (e - v * 125);
    int bvn = (b * 8 + v) * 1000 + n;
    const float4* nd4 = (const float4*)(node_dyn + (size_t)bvn * 8);
    float4 ndA = nd4[0], ndB = nd4[1];
    const float4* gk4 = (const float4*)(gKs + ((size_t)(h * 8 + b) * 1000 + n) * 32);
    const float4* gq4 = (const float4*)(gq + v * 32);
    float s = 0.f;
    #pragma unroll
    for (int k4 = 0; k4 < 8; k4++) {
      float4 g = gk4[k4], q = gq4[k4];
      s += g.x*q.x + g.y*q.y + g.z*q.z + g.w*q.w;
    }
    const float* qm = qmk + v * 8;
    float dyn = ndA.x*qm[0] + ndA.y*qm[1] + ndA.z*qm[2] + ndA.w*qm[3]
              + ndB.x*qm[4] + ndB.y*qm[5] + ndB.z*qm[6] + ndB.w*qm[7];
    bool on = bytemode ? (((const unsigned char*)maskp)[bvn] != 0)
                       : (((const int*)maskp)[bvn] != 0);
    float cc = (s + dyn) * 0.17677669529663687f + (on ? 0.f : -INFINITY);
    float pv = __expf(cc);
    p[e] = pv;
    tsum += pv;
  }
  tsum = waveSum(tsum);
  if ((tid & 63) == 0) red4[tid >> 6] = tsum;
  __syncthreads();
  if (tid == 0) csum_p[blk] = red4[0] + red4[1] + red4[2] + red4[3];
  {
    int v = tid >> 5, k = tid & 31;
    const float* gv = gVs + ((size_t)(h * 8 + b) * 1000 + n0) * 32 + k;
    const float* pr = p + v * 125;
    float a = 0.f;
    #pragma unroll 5
    for (int i = 0; i < 125; i++) a += pr[i] * gv[(size_t)i * 32];
    hstat_p[(size_t)blk * 256 + tid] = a;
  }
  if (tid < 64) {
    int v = tid >> 3, f = tid & 7;
    const float* nd = node_dyn + ((size_t)(b * 8 + v) * 1000 + n0) * 8 + f;
    const float* pr = p + v * 125;
    float a = 0.f;
    #pragma unroll 5
    for (int i = 0; i < 125; i++) a += pr[i] * nd[i * 8];
    s8_p[(size_t)blk * 64 + tid] = a;
  }
}

// ---------------- K_fq: 64 blocks, one (b,v) each ----------------
// reduce partial slots -> conc -> fq -> lqm (to global).
__global__ __launch_bounds__(256) void k_fq(
    const float* __restrict__ po, float* __restrict__ W)
{
  const int blk = blockIdx.x, tid = threadIdx.x;
  const int b = blk & 7, v = (blk >> 3) & 7;
  const float* mwgV    = W + OFF_MW;            // rows 0..255
  const float* mwgL    = W + OFF_MW + 512 * 8;  // rows 512..767
  const float* csum_p  = W + OFF_CSUMP;
  const float* hstat_p = W + OFF_HSTATP;
  const float* s8_p    = W + OFF_S8P;
  float* fqg  = W + OFF_FQ;
  float* lqmg = W + OFF_LQM;

  __shared__ __align__(16) float hstatF[2048];
  __shared__ float csumF[8];
  __shared__ float s8F[512];
  __shared__ __align__(16) float cl[256];
  __shared__ float fql[256];
  __shared__ float part[256];

  for (int h2 = 0; h2 < 8; h2++) {
    float s = 0.f;
    #pragma unroll
    for (int cc = 0; cc < 8; cc++)
      s += hstat_p[(size_t)((h2 << 6) | (cc << 3) | b) * 256 + tid];
    hstatF[h2 * 256 + tid] = s;
  }
  if (tid < 8) {
    float s = 0.f;
    #pragma unroll
    for (int cc = 0; cc < 8; cc++) s += csum_p[(tid << 6) | (cc << 3) | b];
    csumF[tid] = s;
  }
  for (int idx = tid; idx < 512; idx += 256) {
    int h2 = idx >> 6, vf = idx & 63;
    float s = 0.f;
    #pragma unroll
    for (int cc = 0; cc < 8; cc++)
      s += s8_p[(size_t)((h2 << 6) | (cc << 3) | b) * 64 + vf];
    s8F[idx] = s;
  }
  __syncthreads();
  {
    int h2 = tid >> 5, k2 = tid & 31;
    float dyn = 0.f;
    const float* s8pp = s8F + h2 * 64 + v * 8;
    const float* mwp = mwgV + tid * 8;
    #pragma unroll
    for (int f = 0; f < 8; f++) dyn += s8pp[f] * mwp[f];
    cl[tid] = (hstatF[h2 * 256 + v * 32 + k2] + dyn) / csumF[h2];
  }
  __syncthreads();
  {
    float a = 0.f;
    const float4* c4 = (const float4*)cl;
    const float4* w4 = (const float4*)(po + (size_t)tid * 256);
    #pragma unroll 4
    for (int e = 0; e < 64; e++) {
      float4 cv = c4[e], wv = w4[e];
      a += cv.x*wv.x + cv.y*wv.y + cv.z*wv.z + cv.w*wv.w;
    }
    fql[tid] = a;
    fqg[(size_t)(b * 8 + v) * 256 + tid] = a;
  }
  __syncthreads();
  {
    int cc2 = tid >> 3, f = tid & 7;
    float s = 0.f;
    for (int d = cc2 * 8; d < cc2 * 8 + 8; d++) s += fql[d] * mwgL[d * 8 + f];
    part[tid] = s;
  }
  __syncthreads();
  if (tid < 8) {
    float s = 0.f;
    for (int cc2 = 0; cc2 < 32; cc2++) s += part[cc2 * 8 + tid];
    lqmg[(b * 8 + v) * 8 + tid] = s;
  }
}

// ---------------- K_logits: 256 blocks = (b, slice of 32 nodes) -------------
// one (v,n) dot per thread -> per-block slot -> ticket last block -> outputs.
__global__ __launch_bounds__(256) void k_logits(
    const float* __restrict__ lKs, const float* __restrict__ node_dyn,
    const void* __restrict__ maskp, float* __restrict__ W,
    float* __restrict__ out)
{
  const int blk = blockIdx.x, tid = threadIdx.x;
  const int b = blk & 7, slice = blk >> 3;
  const int nn = tid >> 3, v = tid & 7;
  const int n = slice * 32 + nn;
  const bool valid = (n < 1000);
  const int n_c = valid ? n : 999;
  const float* fqg  = W + OFF_FQ;
  const float* lqmg = W + OFF_LQM;
  float* expsum_p = W + OFF_EXPSP;
  unsigned long long* packed_p = (unsigned long long*)(W + OFF_PACKP);
  unsigned* done = (unsigned*)(W + OFF_DONE);

  __shared__ float red4[4];
  __shared__ unsigned long long rP[4];
  __shared__ unsigned ticket;
  __shared__ int bmS;

  int bytemode = probeByteMode(maskp, tid, &bmS);   // parallel, ~2 load latencies

  int bvn = (b * 8 + v) * 1000 + n_c;
  const float4* A  = (const float4*)(fqg + (size_t)(b * 8 + v) * 256);
  const float4* Bk = (const float4*)(lKs + ((size_t)(b * 1000 + n_c)) * 256);
  float s = 0.f;
  #pragma unroll 8
  for (int d4 = 0; d4 < 64; d4++) {
    float4 x = A[d4], y = Bk[d4];
    s += x.x*y.x + x.y*y.y + x.z*y.z + x.w*y.w;
  }
  const float4* nd4 = (const float4*)(node_dyn + (size_t)bvn * 8);
  float4 na = nd4[0], nb = nd4[1];
  const float* qm = lqmg + (b * 8 + v) * 8;
  float dyn = na.x*qm[0] + na.y*qm[1] + na.z*qm[2] + na.w*qm[3]
            + nb.x*qm[4] + nb.y*qm[5] + nb.z*qm[6] + nb.w*qm[7];
  float z = (s + dyn) * 0.0625f;
  bool on = bytemode ? (((const unsigned char*)maskp)[bvn] != 0)
                     : (((const int*)maskp)[bvn] != 0);
  float L = tanhf(z) * 10.0f + (on ? 0.f : -INFINITY);
  if (!valid) L = -INFINITY;
  float ex = __expf(L);                     // exp(-inf)=0
  unsigned idx = (unsigned)(v * 1000 + n_c);
  unsigned long long pk = ((unsigned long long)encF(L) << 32) | (unsigned)(~idx);
  float sEx = waveSum(ex);
  unsigned long long mP = waveMaxU(pk);
  if ((tid & 63) == 0) { red4[tid >> 6] = sEx; rP[tid >> 6] = mP; }
  __syncthreads();
  if (tid == 0) {
    float S = red4[0] + red4[1] + red4[2] + red4[3];
    unsigned long long P = rP[0];
    #pragma unroll
    for (int i = 1; i < 4; i++) P = (rP[i] > P) ? rP[i] : P;
    atomicExch(&expsum_p[blk], S);          // coherent-point slot stores
    atomicExch(&packed_p[blk], P);
    __threadfence();
    ticket = atomicAdd(done, 1u);
  }
  __syncthreads();
  if (ticket == 255) {                      // last block: all slots written
    __threadfence();
    if (tid < 64) {
      float cEnt = 0.f;
      if (tid < 8) {
        float S = 0.f;
        unsigned long long P = 0ull;
        for (int sl = 0; sl < 32; sl++) {
          int j = sl * 8 + tid;             // slots of batch tid
          S += atomicAdd(&expsum_p[j], 0.0f);
          unsigned long long q = atomicAdd(&packed_p[j], 0ull);
          P = (q > P) ? q : P;
        }
        float best = decF((unsigned)(P >> 32));
        unsigned bi = ~(unsigned)(P & 0xffffffffu);
        float logprob = best - logf(S);
        float prob = __expf(logprob);
        out[tid]      = (float)(bi / 1000);
        out[8 + tid]  = (float)(bi % 1000);
        out[16 + tid] = logprob;
        cEnt = prob * logprob;
      }
      cEnt = waveSum(cEnt);
      if (tid == 0) out[24] = -cEnt;
    }
  }
}

extern "C" void kernel_launch(void* const* d_in, const int* in_sizes, int n_in,
                              void* d_out, int out_size, void* d_ws, size_t ws_size,
                              hipStream_t stream) {
  const float* fixedc   = (const float*)d_in[1];
  const float* prev     = (const float*)d_in[2];
  const float* node_dyn = (const float*)d_in[3];
  const float* veh      = (const float*)d_in[4];
  const float* gVs      = (const float*)d_in[5];
  const float* gKs      = (const float*)d_in[6];
  const float* lKs      = (const float*)d_in[7];
  const void*  mask     = d_in[8];
  const float* pcs      = (const float*)d_in[9];
  const float* pns1     = (const float*)d_in[10];
  const float* pns2     = (const float*)d_in[11];
  const float* po       = (const float*)d_in[12];
  float* W   = (float*)d_ws;
  float* out = (float*)d_out;

  k_prep<<<832, 256, 0, stream>>>(pns1, pns2, prev, veh, fixedc, pcs, W);
  k_attn<<<512, 256, 0, stream>>>(node_dyn, gVs, gKs, mask, W);
  k_fq<<<64, 256, 0, stream>>>(po, W);
  k_logits<<<256, 256, 0, stream>>>(lKs, node_dyn, mask, W, out);
}

// Round 10
// 157.799 us; speedup vs baseline: 2.3208x; 1.0152x over previous
//
#include <hip/hip_runtime.h>
#include <math.h>

// Problem: B=8, V=8, N=1000, D=256, H=8, KS=32
// 4 launches. Rules learned r3-r9: sync ONLY at kernel boundaries (~4us each;
// intra-kernel cross-XCD sync = 60-100us); keep phases wide (r7: 64-block
// serial-stage kernel = 66us); no redundant strided Mw recompute (r6: 88us);
// no serial global probes (r8: ~25us/block); probe ONCE in k_prep (r10).
//
// ws float offsets — partial-slot handoff, NO zero-init required.
#define OFF_MW     0          // 768*8 = 6144 (rows 0..255 V, 256..511 K, 512..767 L)
#define OFF_QUERY  6144       // 64*256 -> 22528
#define OFF_CSUMP  22528      // [512]      -> 23040
#define OFF_HSTATP 23040      // [512*256]  -> 154112
#define OFF_S8P    154112     // [512*64]   -> 186880
#define OFF_FQ     186880     // [64*256]   -> 203264
#define OFF_LQM    203264     // [64*8]     -> 203776
#define OFF_EXPSP  203776     // [256]      -> 204032
#define OFF_PACKP  204032     // [256 u64]  -> 204544 (byte-offset %8 == 0)
#define OFF_DONE   204544     // [1] zeroed by k_prep
#define OFF_BM     204545     // [1] mask dtype flag, written by k_prep

__device__ inline float waveSum(float v){
  #pragma unroll
  for (int o = 32; o > 0; o >>= 1) v += __shfl_down(v, o, 64);
  return v;
}
__device__ inline unsigned long long waveMaxU(unsigned long long v){
  #pragma unroll
  for (int o = 32; o > 0; o >>= 1) {
    unsigned long long w = __shfl_down(v, o, 64);
    v = (w > v) ? w : v;
  }
  return v;
}
__device__ inline unsigned encF(float f){
  unsigned u = __float_as_uint(f);
  return (u & 0x80000000u) ? ~u : (u | 0x80000000u);
}
__device__ inline float decF(unsigned u){
  return (u & 0x80000000u) ? __uint_as_float(u & 0x7fffffffu)
                           : __uint_as_float(~u);
}

// ---------------- K_prep: 833 blocks ----------------
// [0,768): Mw row per block (coalesced); [768,832): query per (b,v);
// 832: parallel mask-dtype probe + DONE zero.
__global__ __launch_bounds__(256) void k_prep(
    const float* __restrict__ pns1, const float* __restrict__ pns2,
    const float* __restrict__ prev, const float* __restrict__ veh,
    const float* __restrict__ fixedc, const float* __restrict__ pcs,
    const void* __restrict__ maskp, float* __restrict__ W)
{
  int blk = blockIdx.x, tid = threadIdx.x;
  float* mw     = W + OFF_MW;
  float* queryp = W + OFF_QUERY;

  if (blk < 768) {
    // Mw[i][f<7] = pns1[i,f] + sum_j pns2[i,j]*pns1[j,f]; Mw[i][7]=pns2[i,768]
    int i = blk;
    __shared__ float red[28];
    const float* row = pns2 + (size_t)i * 769;
    float acc[7] = {0.f,0.f,0.f,0.f,0.f,0.f,0.f};
    #pragma unroll
    for (int t = 0; t < 3; t++) {
      int j = tid + 256 * t;              // lane-contiguous: coalesced
      float r = row[j];
      const float* w = pns1 + j * 7;
      #pragma unroll
      for (int f = 0; f < 7; f++) acc[f] += r * w[f];
    }
    #pragma unroll
    for (int f = 0; f < 7; f++) {
      float v = waveSum(acc[f]);
      if ((tid & 63) == 0) red[(tid >> 6) * 7 + f] = v;
    }
    __syncthreads();
    if (tid < 7) {
      float s = red[tid] + red[7 + tid] + red[14 + tid] + red[21 + tid];
      mw[i * 8 + tid] = pns1[i * 7 + tid] + s;
    } else if (tid == 7) {
      mw[i * 8 + 7] = row[768];
    }
  } else if (blk < 832) {
    int bv = blk - 768;
    __shared__ __align__(16) float cvs[264];
    cvs[tid] = prev[(size_t)bv * 256 + tid];
    if (tid < 8) cvs[256 + tid] = veh[bv * 8 + tid];
    __syncthreads();
    int b = bv >> 3;
    float a = fixedc[b * 256 + tid];
    const float4* c4 = (const float4*)cvs;
    const float4* w4 = (const float4*)(pcs + (size_t)tid * 264);
    #pragma unroll 4
    for (int k = 0; k < 66; k++) {
      float4 cv = c4[k], wv = w4[k];
      a += cv.x*wv.x + cv.y*wv.y + cv.z*wv.z + cv.w*wv.w;
    }
    queryp[(size_t)bv * 256 + tid] = a;
  } else {
    // parallel mask-dtype probe: int32 bool has bytes idx%4!=0 all zero;
    // u8 bool has ~70% of them nonzero. One byte per thread + ballot.
    __shared__ unsigned hits[4];
    const unsigned char* mb = (const unsigned char*)maskp;
    bool hit = (tid > 0) && ((tid & 3) != 0) && (mb[tid] != 0);
    unsigned long long bal = __ballot(hit);
    if ((tid & 63) == 0) hits[tid >> 6] = (bal != 0ull) ? 1u : 0u;
    __syncthreads();
    if (tid == 0) {
      ((unsigned*)(W + OFF_BM))[0] = hits[0] | hits[1] | hits[2] | hits[3];
      ((unsigned*)(W + OFF_DONE))[0] = 0u;
    }
  }
}

// ---------------- K_attn: 512 blocks = (h, c, b) ----------------
// compat -> exp (no max-sub; shift-invariant) -> partial slots (plain stores).
__global__ __launch_bounds__(256) void k_attn(
    const float* __restrict__ node_dyn, const float* __restrict__ gVs,
    const float* __restrict__ gKs, const void* __restrict__ maskp,
    float* __restrict__ W)
{
  const int blk = blockIdx.x, tid = threadIdx.x;
  const int b = blk & 7, c = (blk >> 3) & 7, h = blk >> 6;
  const int n0 = c * 125;
  const float* mw     = W + OFF_MW;
  const float* queryp = W + OFF_QUERY;
  float* csum_p  = W + OFF_CSUMP;
  float* hstat_p = W + OFF_HSTATP;
  float* s8_p    = W + OFF_S8P;
  const int bytemode = *(const int*)(W + OFF_BM);   // uniform scalar load

  __shared__ __align__(16) float p[1000];
  __shared__ __align__(16) float gq[256];
  __shared__ float qmk[64];
  __shared__ float red4[4];
  __shared__ float s8part[256];

  gq[tid] = queryp[(size_t)(b * 8 + (tid >> 5)) * 256 + h * 32 + (tid & 31)];
  __syncthreads();
  if (tid < 64) {
    int v = tid >> 3, f = tid & 7;
    float a = 0.f;
    for (int k = 0; k < 32; k++)
      a += gq[v * 32 + k] * mw[(256 + h * 32 + k) * 8 + f];
    qmk[tid] = a;
  }
  __syncthreads();

  float tsum = 0.f;
  for (int e = tid; e < 1000; e += 256) {
    int v = e / 125;
    int n = n0 + (e - v * 125);
    int bvn = (b * 8 + v) * 1000 + n;
    const float4* nd4 = (const float4*)(node_dyn + (size_t)bvn * 8);
    float4 ndA = nd4[0], ndB = nd4[1];
    const float4* gk4 = (const float4*)(gKs + ((size_t)(h * 8 + b) * 1000 + n) * 32);
    const float4* gq4 = (const float4*)(gq + v * 32);
    float s = 0.f;
    #pragma unroll
    for (int k4 = 0; k4 < 8; k4++) {
      float4 g = gk4[k4], q = gq4[k4];
      s += g.x*q.x + g.y*q.y + g.z*q.z + g.w*q.w;
    }
    const float* qm = qmk + v * 8;
    float dyn = ndA.x*qm[0] + ndA.y*qm[1] + ndA.z*qm[2] + ndA.w*qm[3]
              + ndB.x*qm[4] + ndB.y*qm[5] + ndB.z*qm[6] + ndB.w*qm[7];
    bool on = bytemode ? (((const unsigned char*)maskp)[bvn] != 0)
                       : (((const int*)maskp)[bvn] != 0);
    float cc = (s + dyn) * 0.17677669529663687f + (on ? 0.f : -INFINITY);
    float pv = __expf(cc);
    p[e] = pv;
    tsum += pv;
  }
  tsum = waveSum(tsum);
  if ((tid & 63) == 0) red4[tid >> 6] = tsum;
  __syncthreads();
  if (tid == 0) csum_p[blk] = red4[0] + red4[1] + red4[2] + red4[3];
  // hstat partial [v][k] — all 256 threads
  {
    int v = tid >> 5, k = tid & 31;
    const float* gv = gVs + ((size_t)(h * 8 + b) * 1000 + n0) * 32 + k;
    const float* pr = p + v * 125;
    float a = 0.f;
    #pragma unroll 5
    for (int i = 0; i < 125; i++) a += pr[i] * gv[(size_t)i * 32];
    hstat_p[(size_t)blk * 256 + tid] = a;
  }
  // s8 partial [v][f] — 4-way split across all 256 threads (r10: was 64 thr)
  {
    int sidx = tid & 3, vf = tid >> 2;
    int v = vf >> 3, f = vf & 7;
    int i0 = sidx * 32;
    int iN = (sidx == 3) ? 29 : 32;          // 32+32+32+29 = 125
    const float* nd = node_dyn + ((size_t)(b * 8 + v) * 1000 + n0 + i0) * 8 + f;
    const float* pr = p + v * 125 + i0;
    float a = 0.f;
    for (int i = 0; i < iN; i++) a += pr[i] * nd[i * 8];
    s8part[sidx * 64 + vf] = a;
  }
  __syncthreads();
  if (tid < 64)
    s8_p[(size_t)blk * 64 + tid] = s8part[tid] + s8part[64 + tid]
                                 + s8part[128 + tid] + s8part[192 + tid];
}

// ---------------- K_fq: 64 blocks, one (b,v) each ----------------
// reduce partial slots -> conc -> fq -> lqm (to global).
__global__ __launch_bounds__(256) void k_fq(
    const float* __restrict__ po, float* __restrict__ W)
{
  const int blk = blockIdx.x, tid = threadIdx.x;
  const int b = blk & 7, v = (blk >> 3) & 7;
  const float* mwgV    = W + OFF_MW;            // rows 0..255
  const float* mwgL    = W + OFF_MW + 512 * 8;  // rows 512..767
  const float* csum_p  = W + OFF_CSUMP;
  const float* hstat_p = W + OFF_HSTATP;
  const float* s8_p    = W + OFF_S8P;
  float* fqg  = W + OFF_FQ;
  float* lqmg = W + OFF_LQM;

  __shared__ __align__(16) float hstatF[2048];
  __shared__ float csumF[8];
  __shared__ float s8F[512];
  __shared__ __align__(16) float cl[256];
  __shared__ float fql[256];
  __shared__ float part[256];

  for (int h2 = 0; h2 < 8; h2++) {
    float s = 0.f;
    #pragma unroll
    for (int cc = 0; cc < 8; cc++)
      s += hstat_p[(size_t)((h2 << 6) | (cc << 3) | b) * 256 + tid];
    hstatF[h2 * 256 + tid] = s;
  }
  if (tid < 8) {
    float s = 0.f;
    #pragma unroll
    for (int cc = 0; cc < 8; cc++) s += csum_p[(tid << 6) | (cc << 3) | b];
    csumF[tid] = s;
  }
  for (int idx = tid; idx < 512; idx += 256) {
    int h2 = idx >> 6, vf = idx & 63;
    float s = 0.f;
    #pragma unroll
    for (int cc = 0; cc < 8; cc++)
      s += s8_p[(size_t)((h2 << 6) | (cc << 3) | b) * 64 + vf];
    s8F[idx] = s;
  }
  __syncthreads();
  {
    int h2 = tid >> 5, k2 = tid & 31;
    float dyn = 0.f;
    const float* s8pp = s8F + h2 * 64 + v * 8;
    const float* mwp = mwgV + tid * 8;
    #pragma unroll
    for (int f = 0; f < 8; f++) dyn += s8pp[f] * mwp[f];
    cl[tid] = (hstatF[h2 * 256 + v * 32 + k2] + dyn) / csumF[h2];
  }
  __syncthreads();
  {
    float a = 0.f;
    const float4* c4 = (const float4*)cl;
    const float4* w4 = (const float4*)(po + (size_t)tid * 256);
    #pragma unroll 4
    for (int e = 0; e < 64; e++) {
      float4 cv = c4[e], wv = w4[e];
      a += cv.x*wv.x + cv.y*wv.y + cv.z*wv.z + cv.w*wv.w;
    }
    fql[tid] = a;
    fqg[(size_t)(b * 8 + v) * 256 + tid] = a;
  }
  __syncthreads();
  {
    int cc2 = tid >> 3, f = tid & 7;
    float s = 0.f;
    for (int d = cc2 * 8; d < cc2 * 8 + 8; d++) s += fql[d] * mwgL[d * 8 + f];
    part[tid] = s;
  }
  __syncthreads();
  if (tid < 8) {
    float s = 0.f;
    for (int cc2 = 0; cc2 < 32; cc2++) s += part[cc2 * 8 + tid];
    lqmg[(b * 8 + v) * 8 + tid] = s;
  }
}

// ---------------- K_logits: 256 blocks = (b, slice of 32 nodes) -------------
// one (v,n) dot per thread -> per-block slot -> ticket last block -> outputs.
__global__ __launch_bounds__(256) void k_logits(
    const float* __restrict__ lKs, const float* __restrict__ node_dyn,
    const void* __restrict__ maskp, float* __restrict__ W,
    float* __restrict__ out)
{
  const int blk = blockIdx.x, tid = threadIdx.x;
  const int b = blk & 7, slice = blk >> 3;
  const int nn = tid >> 3, v = tid & 7;
  const int n = slice * 32 + nn;
  const bool valid = (n < 1000);
  const int n_c = valid ? n : 999;
  const float* fqg  = W + OFF_FQ;
  const float* lqmg = W + OFF_LQM;
  float* expsum_p = W + OFF_EXPSP;
  unsigned long long* packed_p = (unsigned long long*)(W + OFF_PACKP);
  unsigned* done = (unsigned*)(W + OFF_DONE);
  const int bytemode = *(const int*)(W + OFF_BM);   // uniform scalar load

  __shared__ float red4[4];
  __shared__ unsigned long long rP[4];
  __shared__ unsigned ticket;

  int bvn = (b * 8 + v) * 1000 + n_c;
  const float4* A  = (const float4*)(fqg + (size_t)(b * 8 + v) * 256);
  const float4* Bk = (const float4*)(lKs + ((size_t)(b * 1000 + n_c)) * 256);
  float s = 0.f;
  #pragma unroll 8
  for (int d4 = 0; d4 < 64; d4++) {
    float4 x = A[d4], y = Bk[d4];
    s += x.x*y.x + x.y*y.y + x.z*y.z + x.w*y.w;
  }
  const float4* nd4 = (const float4*)(node_dyn + (size_t)bvn * 8);
  float4 na = nd4[0], nb = nd4[1];
  const float* qm = lqmg + (b * 8 + v) * 8;
  float dyn = na.x*qm[0] + na.y*qm[1] + na.z*qm[2] + na.w*qm[3]
            + nb.x*qm[4] + nb.y*qm[5] + nb.z*qm[6] + nb.w*qm[7];
  float z = (s + dyn) * 0.0625f;
  bool on = bytemode ? (((const unsigned char*)maskp)[bvn] != 0)
                     : (((const int*)maskp)[bvn] != 0);
  float L = tanhf(z) * 10.0f + (on ? 0.f : -INFINITY);
  if (!valid) L = -INFINITY;
  float ex = __expf(L);                     // exp(-inf)=0
  unsigned idx = (unsigned)(v * 1000 + n_c);
  unsigned long long pk = ((unsigned long long)encF(L) << 32) | (unsigned)(~idx);
  float sEx = waveSum(ex);
  unsigned long long mP = waveMaxU(pk);
  if ((tid & 63) == 0) { red4[tid >> 6] = sEx; rP[tid >> 6] = mP; }
  __syncthreads();
  if (tid == 0) {
    float S = red4[0] + red4[1] + red4[2] + red4[3];
    unsigned long long P = rP[0];
    #pragma unroll
    for (int i = 1; i < 4; i++) P = (rP[i] > P) ? rP[i] : P;
    atomicExch(&expsum_p[blk], S);          // coherent-point slot stores
    atomicExch(&packed_p[blk], P);
    __threadfence();
    ticket = atomicAdd(done, 1u);
  }
  __syncthreads();
  if (ticket == 255) {                      // last block: all slots written
    __threadfence();
    if (tid < 64) {
      float cEnt = 0.f;
      if (tid < 8) {
        float S = 0.f;
        unsigned long long P = 0ull;
        for (int sl = 0; sl < 32; sl++) {
          int j = sl * 8 + tid;             // slots of batch tid
          S += atomicAdd(&expsum_p[j], 0.0f);
          unsigned long long q = atomicAdd(&packed_p[j], 0ull);
          P = (q > P) ? q : P;
        }
        float best = decF((unsigned)(P >> 32));
        unsigned bi = ~(unsigned)(P & 0xffffffffu);
        float logprob = best - logf(S);
        float prob = __expf(logprob);
        out[tid]      = (float)(bi / 1000);
        out[8 + tid]  = (float)(bi % 1000);
        out[16 + tid] = logprob;
        cEnt = prob * logprob;
      }
      cEnt = waveSum(cEnt);
      if (tid == 0) out[24] = -cEnt;
    }
  }
}

extern "C" void kernel_launch(void* const* d_in, const int* in_sizes, int n_in,
                              void* d_out, int out_size, void* d_ws, size_t ws_size,
                              hipStream_t stream) {
  const float* fixedc   = (const float*)d_in[1];
  const float* prev     = (const float*)d_in[2];
  const float* node_dyn = (const float*)d_in[3];
  const float* veh      = (const float*)d_in[4];
  const float* gVs      = (const float*)d_in[5];
  const float* gKs      = (const float*)d_in[6];
  const float* lKs      = (const float*)d_in[7];
  const void*  mask     = d_in[8];
  const float* pcs      = (const float*)d_in[9];
  const float* pns1     = (const float*)d_in[10];
  const float* pns2     = (const float*)d_in[11];
  const float* po       = (const float*)d_in[12];
  float* W   = (float*)d_ws;
  float* out = (float*)d_out;

  k_prep<<<833, 256, 0, stream>>>(pns1, pns2, prev, veh, fixedc, pcs, mask, W);
  k_attn<<<512, 256, 0, stream>>>(node_dyn, gVs, gKs, mask, W);
  k_fq<<<64, 256, 0, stream>>>(po, W);
  k_logits<<<256, 256, 0, stream>>>(lKs, node_dyn, mask, W, out);
}